// Round 6
// baseline (2682.753 us; speedup 1.0000x reference)
//
#include <hip/hip_runtime.h>
#include <hip/hip_bf16.h>

#define NPTS 200000
#define NVOX 60000
#define NB 4
#define KK 27

// ---- mask encoding: 0 = uint8 bool, 1 = int32, 2 = float32 ----
__device__ __forceinline__ float get_mask(const void* nm, int fl, long i) {
    if (fl == 0) return ((const unsigned char*)nm)[i] ? 1.0f : 0.0f;
    if (fl == 1) return ((const int*)nm)[i] ? 1.0f : 0.0f;
    return ((const float*)nm)[i];
}

// ---- init: zero scratch + detect mask encoding (block 0) ----
__global__ void k_init(float* zbase, int nz, const unsigned int* nm, int* flag) {
    for (int i = blockIdx.x * 256 + threadIdx.x; i < nz; i += gridDim.x * 256)
        zbase[i] = 0.f;
    if (blockIdx.x == 0) {
        __shared__ int cntF, cntI;
        if (threadIdx.x == 0) { cntF = 0; cntI = 0; }
        __syncthreads();
        int f = 0, i1 = 0;
        for (int i = threadIdx.x; i < 1024; i += 256) {
            unsigned int v = nm[i];
            if (v == 0x3f800000u) f++;
            if (v == 1u) i1++;
        }
        atomicAdd(&cntF, f); atomicAdd(&cntI, i1);
        __syncthreads();
        if (threadIdx.x == 0)
            *flag = (cntF > 100) ? 2 : ((cntI > 100) ? 1 : 0);
    }
}

// ---- voxelize: scatter-add points into voxels (raw sums; divide fused into conv1) ----
__global__ void k_scatter(const float4* __restrict__ feat, const int* __restrict__ p2v,
                          float* cnt, float* vox) {
    int p = blockIdx.x * 256 + threadIdx.x;
    if (p >= NPTS) return;
    int v = p2v[p];
    float4 f = feat[p];
    atomicAdd(&cnt[v], 1.0f);
    atomicAdd(&vox[v * 4 + 0], f.x);
    atomicAdd(&vox[v * 4 + 1], f.y);
    atomicAdd(&vox[v * 4 + 2], f.z);
    atomicAdd(&vox[v * 4 + 3], f.w);
}

// ---- conv1: Cin=4 -> Cout=32; thread=(voxel, quad of 8 ch); full unroll, no local arrays ----
__global__ __launch_bounds__(256, 4) void k_conv1(
        const float* __restrict__ vox, const float* __restrict__ cnt,
        const float* __restrict__ W1,
        const float* __restrict__ g1, const float* __restrict__ b1,
        const int* __restrict__ nidx, const void* __restrict__ nmask,
        const int* __restrict__ flag, float* __restrict__ h1) {
    int tid = threadIdx.x;
    int vl = tid & 63;
    int q = __builtin_amdgcn_readfirstlane(tid >> 6);   // wave-uniform quad
    int v = blockIdx.x * 64 + vl;
    int vc = v < NVOX ? v : NVOX - 1;
    int fl = *flag;
    float acc[8];
#pragma unroll
    for (int d = 0; d < 8; d++) acc[d] = 0.f;
#pragma unroll
    for (int k = 0; k < KK; k++) {          // FULL unroll: all indices static, no scratch
        int idx = nidx[k * NVOX + vc];
        float m = get_mask(nmask, fl, (long)k * NVOX + vc);
        float4 r = ((const float4*)vox)[idx];
        float mm = m / fmaxf(cnt[idx], 1.0f);   // 0 when masked; fused voxel average
        const float* wk = W1 + k * 128 + q * 8; // wave-uniform -> s_load (W1 fits sL1)
#pragma unroll
        for (int c = 0; c < 4; c++) {
            float rc = (c == 0 ? r.x : c == 1 ? r.y : c == 2 ? r.z : r.w) * mm;
#pragma unroll
            for (int d = 0; d < 8; d++) acc[d] = fmaf(rc, wk[c * 32 + d], acc[d]);
        }
    }
    if (v < NVOX) {
        const float* gp = g1 + q * 8;
        const float* bp = b1 + q * 8;
        float o[8];
#pragma unroll
        for (int d = 0; d < 8; d++) o[d] = fmaxf(acc[d] * gp[d] + bp[d], 0.f);
        float4* op = (float4*)(h1 + (size_t)v * 32 + q * 8);
        op[0] = make_float4(o[0], o[1], o[2], o[3]);
        op[1] = make_float4(o[4], o[5], o[6], o[7]);
    }
}

// ---- conv2: 512 thr = 64 vox x 2 half x 4 kc; branchless; vector-broadcast weights ----
__global__ __launch_bounds__(512, 4) void k_conv2(
        const float* __restrict__ h1, const float* __restrict__ W2,
        const float* __restrict__ g2, const float* __restrict__ b2,
        const int* __restrict__ nidx, const void* __restrict__ nmask,
        const int* __restrict__ flag, float* __restrict__ h2) {
    __shared__ float part[3][64][33];
    int tid = threadIdx.x;
    int vl = tid & 63;
    int half = __builtin_amdgcn_readfirstlane((tid >> 6) & 1);  // wave-uniform
    int kc   = __builtin_amdgcn_readfirstlane(tid >> 7);        // wave-uniform
    int v = blockIdx.x * 64 + vl;
    int vc = v < NVOX ? v : NVOX - 1;
    int fl = *flag;
    int k0 = kc * 7;
    int nk = (kc == 3) ? 6 : 7;   // chunks 7,7,7,6 (uniform branch)
    const float* Wh = W2 + half * 16;
    // opaque zero in a VGPR: forces weight reads onto the VECTOR memory path
    // (wave-uniform address -> one broadcast request; deep vmcnt pipelining,
    //  avoids thrashing the 16KB scalar L1 with W2's 110KB stream)
    int vzero;
    asm volatile("v_mov_b32 %0, 0" : "=v"(vzero));
    float acc[16];
#pragma unroll
    for (int d = 0; d < 16; d++) acc[d] = 0.f;

    float4 bufA[8], bufB[8];
    float mcur;
    {   // prime j=0 (unconditional)
        int idx0 = nidx[k0 * NVOX + vc];
        mcur = get_mask(nmask, fl, (long)k0 * NVOX + vc);
        const float4* rp = (const float4*)(h1 + (size_t)idx0 * 32);
#pragma unroll
        for (int qq = 0; qq < 8; qq++) bufA[qq] = rp[qq];
    }
#pragma unroll
    for (int j = 0; j < 7; j++) {
        float4* cur = (j & 1) ? bufB : bufA;   // static after full unroll
        float4* nxt = (j & 1) ? bufA : bufB;
        float mnxt = 0.f;
        if (j + 1 < nk) {   // prefetch next row unconditionally (branchless wrt mask)
            int k = k0 + j + 1;
            int idxn = nidx[k * NVOX + vc];
            mnxt = get_mask(nmask, fl, (long)k * NVOX + vc);
            const float4* rp = (const float4*)(h1 + (size_t)idxn * 32);
#pragma unroll
            for (int qq = 0; qq < 8; qq++) nxt[qq] = rp[qq];
        }
        if (j < nk) {
            const float* wk = Wh + (k0 + j) * 1024 + vzero;
#pragma unroll
            for (int c = 0; c < 32; c++) {
                float4 aq = cur[c >> 2];
                float rc = ((c & 3) == 0 ? aq.x : (c & 3) == 1 ? aq.y :
                            (c & 3) == 2 ? aq.z : aq.w) * mcur;
                const float4* wv = (const float4*)(wk + c * 32);
                float4 w0 = wv[0], w1 = wv[1], w2 = wv[2], w3 = wv[3];
                acc[0]  = fmaf(rc, w0.x, acc[0]);  acc[1]  = fmaf(rc, w0.y, acc[1]);
                acc[2]  = fmaf(rc, w0.z, acc[2]);  acc[3]  = fmaf(rc, w0.w, acc[3]);
                acc[4]  = fmaf(rc, w1.x, acc[4]);  acc[5]  = fmaf(rc, w1.y, acc[5]);
                acc[6]  = fmaf(rc, w1.z, acc[6]);  acc[7]  = fmaf(rc, w1.w, acc[7]);
                acc[8]  = fmaf(rc, w2.x, acc[8]);  acc[9]  = fmaf(rc, w2.y, acc[9]);
                acc[10] = fmaf(rc, w2.z, acc[10]); acc[11] = fmaf(rc, w2.w, acc[11]);
                acc[12] = fmaf(rc, w3.x, acc[12]); acc[13] = fmaf(rc, w3.y, acc[13]);
                acc[14] = fmaf(rc, w3.z, acc[14]); acc[15] = fmaf(rc, w3.w, acc[15]);
            }
        }
        mcur = mnxt;
    }
    if (kc > 0) {
#pragma unroll
        for (int d = 0; d < 16; d++) part[kc - 1][vl][half * 16 + d] = acc[d];
    }
    __syncthreads();
    if (kc == 0 && v < NVOX) {
#pragma unroll
        for (int d = 0; d < 16; d++)
            acc[d] += part[0][vl][half * 16 + d] + part[1][vl][half * 16 + d]
                    + part[2][vl][half * 16 + d];
        const float* gp = g2 + half * 16;
        const float* bp = b2 + half * 16;
        float o[16];
#pragma unroll
        for (int d = 0; d < 16; d++) o[d] = fmaxf(acc[d] * gp[d] + bp[d], 0.f);
        float4* op = (float4*)(h2 + (size_t)v * 32 + half * 16);
#pragma unroll
        for (int qq = 0; qq < 4; qq++)
            op[qq] = make_float4(o[qq * 4], o[qq * 4 + 1], o[qq * 4 + 2], o[qq * 4 + 3]);
    }
}

// ---- per-batch pooling: register accumulation, tiny atomic tail ----
__global__ __launch_bounds__(256) void k_pool(
        const float* __restrict__ h2, const int* __restrict__ vb,
        float* bsum, unsigned int* bmax, float* bcnt) {
    __shared__ float ls[NB * 32];
    __shared__ unsigned int lm[NB * 32];
    __shared__ float lc[NB];
    for (int i = threadIdx.x; i < NB * 32; i += 256) { ls[i] = 0.f; lm[i] = 0u; }
    if (threadIdx.x < NB) lc[threadIdx.x] = 0.f;
    __syncthreads();
    int c = threadIdx.x & 31, slot = threadIdx.x >> 5;
    float s0 = 0, s1 = 0, s2 = 0, s3 = 0, m0 = 0, m1 = 0, m2 = 0, m3 = 0;
    float c0 = 0, c1 = 0, c2 = 0, c3 = 0;
    for (int n = blockIdx.x * 8 + slot; n < NVOX; n += gridDim.x * 8) {
        float vv = h2[(size_t)n * 32 + c];
        int b = vb[n];
        s0 += (b == 0) ? vv : 0.f; m0 = (b == 0) ? fmaxf(m0, vv) : m0;
        s1 += (b == 1) ? vv : 0.f; m1 = (b == 1) ? fmaxf(m1, vv) : m1;
        s2 += (b == 2) ? vv : 0.f; m2 = (b == 2) ? fmaxf(m2, vv) : m2;
        s3 += (b == 3) ? vv : 0.f; m3 = (b == 3) ? fmaxf(m3, vv) : m3;
        if (c == 0) {
            c0 += (b == 0) ? 1.f : 0.f; c1 += (b == 1) ? 1.f : 0.f;
            c2 += (b == 2) ? 1.f : 0.f; c3 += (b == 3) ? 1.f : 0.f;
        }
    }
    atomicAdd(&ls[0 * 32 + c], s0); atomicAdd(&ls[1 * 32 + c], s1);
    atomicAdd(&ls[2 * 32 + c], s2); atomicAdd(&ls[3 * 32 + c], s3);
    atomicMax(&lm[0 * 32 + c], __float_as_uint(m0));  // h2 >= 0
    atomicMax(&lm[1 * 32 + c], __float_as_uint(m1));
    atomicMax(&lm[2 * 32 + c], __float_as_uint(m2));
    atomicMax(&lm[3 * 32 + c], __float_as_uint(m3));
    if (c == 0) {
        atomicAdd(&lc[0], c0); atomicAdd(&lc[1], c1);
        atomicAdd(&lc[2], c2); atomicAdd(&lc[3], c3);
    }
    __syncthreads();
    if (threadIdx.x < NB * 32) {
        atomicAdd(&bsum[threadIdx.x], ls[threadIdx.x]);
        atomicMax(&bmax[threadIdx.x], lm[threadIdx.x]);
    }
    if (threadIdx.x < NB) atomicAdd(&bcnt[threadIdx.x], lc[threadIdx.x]);
}

// ---- channel-attention MLP (tiny, 4 batches) ----
__global__ void k_ca(const float* __restrict__ bsum, const unsigned int* __restrict__ bmax,
                     const float* __restrict__ bcnt,
                     const float* __restrict__ w1, const float* __restrict__ b1,
                     const float* __restrict__ w2, const float* __restrict__ b2,
                     float* ca) {
    int b = threadIdx.x;
    if (b >= NB) return;
    float avg[32], mx[32], o[32];
    float inv = 1.0f / fmaxf(bcnt[b], 1.0f);
#pragma unroll
    for (int c = 0; c < 32; c++) {
        avg[c] = bsum[b * 32 + c] * inv;
        mx[c]  = __uint_as_float(bmax[b * 32 + c]);
        o[c] = 0.f;
    }
#pragma unroll
    for (int pass = 0; pass < 2; pass++) {
        float r[8];
#pragma unroll
        for (int j = 0; j < 8; j++) {
            float s = b1[j];
#pragma unroll
            for (int c = 0; c < 32; c++) s += (pass ? mx[c] : avg[c]) * w1[c * 8 + j];
            r[j] = fmaxf(s, 0.f);
        }
#pragma unroll
        for (int d = 0; d < 32; d++) {
            float s = b2[d];
#pragma unroll
            for (int j = 0; j < 8; j++) s += r[j] * w2[j * 32 + d];
            o[d] += s;
        }
    }
#pragma unroll
    for (int d = 0; d < 32; d++)
        ca[b * 32 + d] = 1.0f / (1.0f + expf(-o[d]));
}

// ---- apply channel attention (in place) + build s2 = [mean_c, max_c]; 2 thr/voxel ----
__global__ void k_apply(float* h2, const float* __restrict__ ca,
                        const int* __restrict__ vb, float* __restrict__ s2) {
    int t = blockIdx.x * 256 + threadIdx.x;
    int v = t >> 1, hf = t & 1;
    if (v >= NVOX) return;
    int b = vb[v];
    float4* hp = (float4*)(h2 + (size_t)v * 32) + hf * 4;
    const float4* cp = (const float4*)(ca + b * 32) + hf * 4;
    float sum = 0.f, mx = 0.f;
#pragma unroll
    for (int q = 0; q < 4; q++) {
        float4 h = hp[q]; float4 c = cp[q];
        h.x *= c.x; h.y *= c.y; h.z *= c.z; h.w *= c.w;
        hp[q] = h;
        sum += h.x + h.y + h.z + h.w;
        mx = fmaxf(mx, fmaxf(fmaxf(h.x, h.y), fmaxf(h.z, h.w)));
    }
    sum += __shfl_xor(sum, 1);
    mx = fmaxf(mx, __shfl_xor(mx, 1));
    if (hf == 0) {
        s2[v * 2 + 0] = sum * (1.0f / 32.0f);
        s2[v * 2 + 1] = mx;
    }
}

// ---- spatial attention: 2-ch sparse conv -> sigmoid; 4 thr/voxel, batch-prefetched ----
__global__ void k_saconv(const float* __restrict__ s2, const float* __restrict__ saW,
                         const int* __restrict__ nidx, const void* __restrict__ nmask,
                         const int* __restrict__ flag, float* __restrict__ sa) {
    __shared__ float w[KK * 2];
    if (threadIdx.x < KK * 2) w[threadIdx.x] = saW[threadIdx.x];
    __syncthreads();
    int t = blockIdx.x * 256 + threadIdx.x;
    int v = t >> 2, q = t & 3;
    if (v >= NVOX) return;
    int fl = *flag;
    float acc = 0.f;
#pragma unroll
    for (int j = 0; j < 7; j++) {
        int k = q + j * 4;
        if (k < KK) {
            int idx = nidx[k * NVOX + v];
            float m = get_mask(nmask, fl, (long)k * NVOX + v);
            float2 s = ((const float2*)s2)[idx];
            acc += m * (s.x * w[k * 2] + s.y * w[k * 2 + 1]);
        }
    }
    acc += __shfl_xor(acc, 1);
    acc += __shfl_xor(acc, 2);
    if (q == 0) sa[v] = 1.0f / (1.0f + expf(-acc));
}

// ---- gather to points, apply sa, classifier; 2 thr/point split over c ----
__global__ __launch_bounds__(256) void k_final(
        const float* __restrict__ h2, const float* __restrict__ sa,
        const int* __restrict__ p2v, const float* __restrict__ clsw,
        const float* __restrict__ clsb, float* __restrict__ out) {
    __shared__ float w[32 * 20];
    __shared__ float bb[20];
    for (int i = threadIdx.x; i < 640; i += 256) w[i] = clsw[i];
    if (threadIdx.x < 20) bb[threadIdx.x] = clsb[threadIdx.x];
    __syncthreads();
    int t = blockIdx.x * 256 + threadIdx.x;
    int p = t >> 1, ch = t & 1;
    if (p >= NPTS) return;
    int v = p2v[p];
    float s = sa[v];
    float acc[20];
#pragma unroll
    for (int j = 0; j < 20; j++) acc[j] = 0.f;
    const float4* hp = (const float4*)(h2 + (size_t)v * 32) + ch * 4;
#pragma unroll
    for (int q = 0; q < 4; q++) {
        float4 h = hp[q];
        int cb = (ch * 16 + q * 4) * 20;
        float z0 = h.x * s, z1 = h.y * s, z2 = h.z * s, z3 = h.w * s;
#pragma unroll
        for (int j = 0; j < 20; j++)
            acc[j] += z0 * w[cb + j] + z1 * w[cb + 20 + j]
                    + z2 * w[cb + 40 + j] + z3 * w[cb + 60 + j];
    }
#pragma unroll
    for (int j = 0; j < 20; j++) acc[j] += __shfl_xor(acc[j], 1);
    if (ch == 0) {
#pragma unroll
        for (int j = 0; j < 20; j++) out[(size_t)p * 20 + j] = acc[j] + bb[j];
    }
}

extern "C" void kernel_launch(void* const* d_in, const int* in_sizes, int n_in,
                              void* d_out, int out_size, void* d_ws, size_t ws_size,
                              hipStream_t stream) {
    const float* feat = (const float*)d_in[0];
    const float* W1   = (const float*)d_in[1];
    const float* g1   = (const float*)d_in[2];
    const float* b1   = (const float*)d_in[3];
    const float* W2   = (const float*)d_in[4];
    const float* g2   = (const float*)d_in[5];
    const float* b2   = (const float*)d_in[6];
    const float* caw1 = (const float*)d_in[7];
    const float* cab1 = (const float*)d_in[8];
    const float* caw2 = (const float*)d_in[9];
    const float* cab2 = (const float*)d_in[10];
    const float* saW  = (const float*)d_in[11];
    const float* clsw = (const float*)d_in[12];
    const float* clsb = (const float*)d_in[13];
    const int* p2v    = (const int*)d_in[14];
    const int* vb     = (const int*)d_in[15];
    const int* nidx   = (const int*)d_in[16];
    const void* nmask = d_in[17];
    float* out = (float*)d_out;

    int* flag   = (int*)d_ws;
    float* cnt  = (float*)d_ws + 64;              // 60000
    float* vox  = cnt + NVOX;                     // 240000 (raw sums)
    float* bsum = vox + (size_t)NVOX * 4;         // 128
    unsigned int* bmax = (unsigned int*)(bsum + NB * 32);  // 128
    float* bcnt = (float*)(bmax + NB * 32);       // 4
    float* ca   = bcnt + 64;                      // 128 (padded region)
    float* h1   = ca + 128;
    float* h2   = h1 + (size_t)NVOX * 32;
    float* s2   = h2 + (size_t)NVOX * 32;
    float* sa   = s2 + (size_t)NVOX * 2;

    int nzero = NVOX * 5 + NB * 32 * 2 + NB + 64;   // cnt..ca region
    k_init<<<512, 256, 0, stream>>>(cnt, nzero, (const unsigned int*)nmask, flag);
    k_scatter<<<(NPTS + 255) / 256, 256, 0, stream>>>((const float4*)feat, p2v, cnt, vox);
    k_conv1<<<(NVOX + 63) / 64, 256, 0, stream>>>(vox, cnt, W1, g1, b1, nidx, nmask, flag, h1);
    k_conv2<<<(NVOX + 63) / 64, 512, 0, stream>>>(h1, W2, g2, b2, nidx, nmask, flag, h2);
    k_pool<<<512, 256, 0, stream>>>(h2, vb, bsum, bmax, bcnt);
    k_ca<<<1, 64, 0, stream>>>(bsum, bmax, bcnt, caw1, cab1, caw2, cab2, ca);
    k_apply<<<(NVOX * 2 + 255) / 256, 256, 0, stream>>>(h2, ca, vb, s2);
    k_saconv<<<(NVOX * 4 + 255) / 256, 256, 0, stream>>>(s2, saW, nidx, nmask, flag, sa);
    k_final<<<(NPTS * 2 + 255) / 256, 256, 0, stream>>>(h2, sa, p2v, clsw, clsb, out);
}

// Round 7
// 564.328 us; speedup vs baseline: 4.7539x; 4.7539x over previous
//
#include <hip/hip_runtime.h>
#include <hip/hip_bf16.h>

#define NPTS 200000
#define NVOX 60000
#define NB 4
#define KK 27

// ---- mask encoding: 0 = uint8 bool, 1 = int32, 2 = float32 ----
__device__ __forceinline__ float get_mask(const void* nm, int fl, long i) {
    if (fl == 0) return ((const unsigned char*)nm)[i] ? 1.0f : 0.0f;
    if (fl == 1) return ((const int*)nm)[i] ? 1.0f : 0.0f;
    return ((const float*)nm)[i];
}

// ---- init: zero scratch + detect mask encoding (block 0) ----
__global__ void k_init(float* zbase, int nz, const unsigned int* nm, int* flag) {
    for (int i = blockIdx.x * 256 + threadIdx.x; i < nz; i += gridDim.x * 256)
        zbase[i] = 0.f;
    if (blockIdx.x == 0) {
        __shared__ int cntF, cntI;
        if (threadIdx.x == 0) { cntF = 0; cntI = 0; }
        __syncthreads();
        int f = 0, i1 = 0;
        for (int i = threadIdx.x; i < 1024; i += 256) {
            unsigned int v = nm[i];
            if (v == 0x3f800000u) f++;
            if (v == 1u) i1++;
        }
        atomicAdd(&cntF, f); atomicAdd(&cntI, i1);
        __syncthreads();
        if (threadIdx.x == 0)
            *flag = (cntF > 100) ? 2 : ((cntI > 100) ? 1 : 0);
    }
}

// ---- voxelize: scatter-add points into voxels (raw sums; divide fused into conv1) ----
__global__ void k_scatter(const float4* __restrict__ feat, const int* __restrict__ p2v,
                          float* cnt, float* vox) {
    int p = blockIdx.x * 256 + threadIdx.x;
    if (p >= NPTS) return;
    int v = p2v[p];
    float4 f = feat[p];
    atomicAdd(&cnt[v], 1.0f);
    atomicAdd(&vox[v * 4 + 0], f.x);
    atomicAdd(&vox[v * 4 + 1], f.y);
    atomicAdd(&vox[v * 4 + 2], f.z);
    atomicAdd(&vox[v * 4 + 3], f.w);
}

// ---- conv1: Cin=4 -> Cout=32; thread=(voxel, quad of 8 ch); full unroll, no local arrays ----
__global__ __launch_bounds__(256, 4) void k_conv1(
        const float* __restrict__ vox, const float* __restrict__ cnt,
        const float* __restrict__ W1,
        const float* __restrict__ g1, const float* __restrict__ b1,
        const int* __restrict__ nidx, const void* __restrict__ nmask,
        const int* __restrict__ flag, float* __restrict__ h1) {
    int tid = threadIdx.x;
    int vl = tid & 63;
    int q = __builtin_amdgcn_readfirstlane(tid >> 6);   // wave-uniform quad
    int v = blockIdx.x * 64 + vl;
    int vc = v < NVOX ? v : NVOX - 1;
    int fl = *flag;
    float acc[8];
#pragma unroll
    for (int d = 0; d < 8; d++) acc[d] = 0.f;
#pragma unroll
    for (int k = 0; k < KK; k++) {          // FULL unroll: all indices static, no scratch
        int idx = nidx[k * NVOX + vc];
        float m = get_mask(nmask, fl, (long)k * NVOX + vc);
        float4 r = ((const float4*)vox)[idx];
        float mm = m / fmaxf(cnt[idx], 1.0f);   // 0 when masked; fused voxel average
        const float* wk = W1 + k * 128 + q * 8; // wave-uniform -> s_load (W1 fits sL1)
#pragma unroll
        for (int c = 0; c < 4; c++) {
            float rc = (c == 0 ? r.x : c == 1 ? r.y : c == 2 ? r.z : r.w) * mm;
#pragma unroll
            for (int d = 0; d < 8; d++) acc[d] = fmaf(rc, wk[c * 32 + d], acc[d]);
        }
    }
    if (v < NVOX) {
        const float* gp = g1 + q * 8;
        const float* bp = b1 + q * 8;
        float o[8];
#pragma unroll
        for (int d = 0; d < 8; d++) o[d] = fmaxf(acc[d] * gp[d] + bp[d], 0.f);
        float4* op = (float4*)(h1 + (size_t)v * 32 + q * 8);
        op[0] = make_float4(o[0], o[1], o[2], o[3]);
        op[1] = make_float4(o[4], o[5], o[6], o[7]);
    }
}

// ---- conv2: 512 thr = 8 waves (half,kc); 2 voxels per lane -> 128 vox/block ----
// 32 FMA per 16-float weight s_load group (2 vox x 16 ch) hides scalar L2 latency.
__global__ __launch_bounds__(512, 4) void k_conv2(
        const float* __restrict__ h1, const float* __restrict__ W2,
        const float* __restrict__ g2, const float* __restrict__ b2,
        const int* __restrict__ nidx, const void* __restrict__ nmask,
        const int* __restrict__ flag, float* __restrict__ h2) {
    __shared__ float part[3][128][33];
    int tid = threadIdx.x;
    int lane = tid & 63;
    int half = __builtin_amdgcn_readfirstlane((tid >> 6) & 1);  // wave-uniform
    int kc   = __builtin_amdgcn_readfirstlane(tid >> 7);        // wave-uniform
    int vA = blockIdx.x * 128 + lane;
    int vB = vA + 64;
    int vcA = vA < NVOX ? vA : NVOX - 1;
    int vcB = vB < NVOX ? vB : NVOX - 1;
    int fl = *flag;
    int k0 = kc * 7;
    int nk = (kc == 3) ? 6 : 7;   // chunks 7,7,7,6 (uniform)
    const float* Wh = W2 + half * 16;
    float accA[16], accB[16];
#pragma unroll
    for (int d = 0; d < 16; d++) { accA[d] = 0.f; accB[d] = 0.f; }

#pragma unroll
    for (int j = 0; j < 7; j++) {
        if (j < nk) {
            int k = k0 + j;
            int idxA = nidx[k * NVOX + vcA];
            int idxB = nidx[k * NVOX + vcB];
            float mA = get_mask(nmask, fl, (long)k * NVOX + vcA);
            float mB = get_mask(nmask, fl, (long)k * NVOX + vcB);
            // 16 independent dwordx4 loads, all issued up front
            const float4* rpA = (const float4*)(h1 + (size_t)idxA * 32);
            const float4* rpB = (const float4*)(h1 + (size_t)idxB * 32);
            float4 rowA[8], rowB[8];
#pragma unroll
            for (int qq = 0; qq < 8; qq++) rowA[qq] = rpA[qq];
#pragma unroll
            for (int qq = 0; qq < 8; qq++) rowB[qq] = rpB[qq];
            const float* wk = Wh + k * 1024;   // wave-uniform -> s_load
#pragma unroll
            for (int c = 0; c < 32; c++) {
                float4 aqA = rowA[c >> 2], aqB = rowB[c >> 2];
                float rcA = ((c & 3) == 0 ? aqA.x : (c & 3) == 1 ? aqA.y :
                             (c & 3) == 2 ? aqA.z : aqA.w) * mA;
                float rcB = ((c & 3) == 0 ? aqB.x : (c & 3) == 1 ? aqB.y :
                             (c & 3) == 2 ? aqB.z : aqB.w) * mB;
                const float* wc = wk + c * 32;
#pragma unroll
                for (int d = 0; d < 16; d++) {
                    float w = wc[d];
                    accA[d] = fmaf(rcA, w, accA[d]);
                    accB[d] = fmaf(rcB, w, accB[d]);
                }
            }
        }
    }
    if (kc > 0) {
#pragma unroll
        for (int d = 0; d < 16; d++) {
            part[kc - 1][lane][half * 16 + d]      = accA[d];
            part[kc - 1][lane + 64][half * 16 + d] = accB[d];
        }
    }
    __syncthreads();
    if (kc == 0) {
        const float* gp = g2 + half * 16;
        const float* bp = b2 + half * 16;
        if (vA < NVOX) {
            float o[16];
#pragma unroll
            for (int d = 0; d < 16; d++) {
                float s = accA[d] + part[0][lane][half * 16 + d]
                        + part[1][lane][half * 16 + d] + part[2][lane][half * 16 + d];
                o[d] = fmaxf(s * gp[d] + bp[d], 0.f);
            }
            float4* op = (float4*)(h2 + (size_t)vA * 32 + half * 16);
#pragma unroll
            for (int qq = 0; qq < 4; qq++)
                op[qq] = make_float4(o[qq * 4], o[qq * 4 + 1], o[qq * 4 + 2], o[qq * 4 + 3]);
        }
        if (vB < NVOX) {
            float o[16];
#pragma unroll
            for (int d = 0; d < 16; d++) {
                float s = accB[d] + part[0][lane + 64][half * 16 + d]
                        + part[1][lane + 64][half * 16 + d] + part[2][lane + 64][half * 16 + d];
                o[d] = fmaxf(s * gp[d] + bp[d], 0.f);
            }
            float4* op = (float4*)(h2 + (size_t)vB * 32 + half * 16);
#pragma unroll
            for (int qq = 0; qq < 4; qq++)
                op[qq] = make_float4(o[qq * 4], o[qq * 4 + 1], o[qq * 4 + 2], o[qq * 4 + 3]);
        }
    }
}

// ---- per-batch pooling: register accumulation, tiny atomic tail ----
__global__ __launch_bounds__(256) void k_pool(
        const float* __restrict__ h2, const int* __restrict__ vb,
        float* bsum, unsigned int* bmax, float* bcnt) {
    __shared__ float ls[NB * 32];
    __shared__ unsigned int lm[NB * 32];
    __shared__ float lc[NB];
    for (int i = threadIdx.x; i < NB * 32; i += 256) { ls[i] = 0.f; lm[i] = 0u; }
    if (threadIdx.x < NB) lc[threadIdx.x] = 0.f;
    __syncthreads();
    int c = threadIdx.x & 31, slot = threadIdx.x >> 5;
    float s0 = 0, s1 = 0, s2 = 0, s3 = 0, m0 = 0, m1 = 0, m2 = 0, m3 = 0;
    float c0 = 0, c1 = 0, c2 = 0, c3 = 0;
    for (int n = blockIdx.x * 8 + slot; n < NVOX; n += gridDim.x * 8) {
        float vv = h2[(size_t)n * 32 + c];
        int b = vb[n];
        s0 += (b == 0) ? vv : 0.f; m0 = (b == 0) ? fmaxf(m0, vv) : m0;
        s1 += (b == 1) ? vv : 0.f; m1 = (b == 1) ? fmaxf(m1, vv) : m1;
        s2 += (b == 2) ? vv : 0.f; m2 = (b == 2) ? fmaxf(m2, vv) : m2;
        s3 += (b == 3) ? vv : 0.f; m3 = (b == 3) ? fmaxf(m3, vv) : m3;
        if (c == 0) {
            c0 += (b == 0) ? 1.f : 0.f; c1 += (b == 1) ? 1.f : 0.f;
            c2 += (b == 2) ? 1.f : 0.f; c3 += (b == 3) ? 1.f : 0.f;
        }
    }
    atomicAdd(&ls[0 * 32 + c], s0); atomicAdd(&ls[1 * 32 + c], s1);
    atomicAdd(&ls[2 * 32 + c], s2); atomicAdd(&ls[3 * 32 + c], s3);
    atomicMax(&lm[0 * 32 + c], __float_as_uint(m0));  // h2 >= 0
    atomicMax(&lm[1 * 32 + c], __float_as_uint(m1));
    atomicMax(&lm[2 * 32 + c], __float_as_uint(m2));
    atomicMax(&lm[3 * 32 + c], __float_as_uint(m3));
    if (c == 0) {
        atomicAdd(&lc[0], c0); atomicAdd(&lc[1], c1);
        atomicAdd(&lc[2], c2); atomicAdd(&lc[3], c3);
    }
    __syncthreads();
    if (threadIdx.x < NB * 32) {
        atomicAdd(&bsum[threadIdx.x], ls[threadIdx.x]);
        atomicMax(&bmax[threadIdx.x], lm[threadIdx.x]);
    }
    if (threadIdx.x < NB) atomicAdd(&bcnt[threadIdx.x], lc[threadIdx.x]);
}

// ---- channel-attention MLP (tiny, 4 batches) ----
__global__ void k_ca(const float* __restrict__ bsum, const unsigned int* __restrict__ bmax,
                     const float* __restrict__ bcnt,
                     const float* __restrict__ w1, const float* __restrict__ b1,
                     const float* __restrict__ w2, const float* __restrict__ b2,
                     float* ca) {
    int b = threadIdx.x;
    if (b >= NB) return;
    float avg[32], mx[32], o[32];
    float inv = 1.0f / fmaxf(bcnt[b], 1.0f);
#pragma unroll
    for (int c = 0; c < 32; c++) {
        avg[c] = bsum[b * 32 + c] * inv;
        mx[c]  = __uint_as_float(bmax[b * 32 + c]);
        o[c] = 0.f;
    }
#pragma unroll
    for (int pass = 0; pass < 2; pass++) {
        float r[8];
#pragma unroll
        for (int j = 0; j < 8; j++) {
            float s = b1[j];
#pragma unroll
            for (int c = 0; c < 32; c++) s += (pass ? mx[c] : avg[c]) * w1[c * 8 + j];
            r[j] = fmaxf(s, 0.f);
        }
#pragma unroll
        for (int d = 0; d < 32; d++) {
            float s = b2[d];
#pragma unroll
            for (int j = 0; j < 8; j++) s += r[j] * w2[j * 32 + d];
            o[d] += s;
        }
    }
#pragma unroll
    for (int d = 0; d < 32; d++)
        ca[b * 32 + d] = 1.0f / (1.0f + expf(-o[d]));
}

// ---- apply channel attention (in place) + build s2 = [mean_c, max_c]; 2 thr/voxel ----
__global__ void k_apply(float* h2, const float* __restrict__ ca,
                        const int* __restrict__ vb, float* __restrict__ s2) {
    int t = blockIdx.x * 256 + threadIdx.x;
    int v = t >> 1, hf = t & 1;
    if (v >= NVOX) return;
    int b = vb[v];
    float4* hp = (float4*)(h2 + (size_t)v * 32) + hf * 4;
    const float4* cp = (const float4*)(ca + b * 32) + hf * 4;
    float sum = 0.f, mx = 0.f;
#pragma unroll
    for (int q = 0; q < 4; q++) {
        float4 h = hp[q]; float4 c = cp[q];
        h.x *= c.x; h.y *= c.y; h.z *= c.z; h.w *= c.w;
        hp[q] = h;
        sum += h.x + h.y + h.z + h.w;
        mx = fmaxf(mx, fmaxf(fmaxf(h.x, h.y), fmaxf(h.z, h.w)));
    }
    sum += __shfl_xor(sum, 1);
    mx = fmaxf(mx, __shfl_xor(mx, 1));
    if (hf == 0) {
        s2[v * 2 + 0] = sum * (1.0f / 32.0f);
        s2[v * 2 + 1] = mx;
    }
}

// ---- spatial attention: 2-ch sparse conv -> sigmoid; 4 thr/voxel ----
__global__ void k_saconv(const float* __restrict__ s2, const float* __restrict__ saW,
                         const int* __restrict__ nidx, const void* __restrict__ nmask,
                         const int* __restrict__ flag, float* __restrict__ sa) {
    __shared__ float w[KK * 2];
    if (threadIdx.x < KK * 2) w[threadIdx.x] = saW[threadIdx.x];
    __syncthreads();
    int t = blockIdx.x * 256 + threadIdx.x;
    int v = t >> 2, q = t & 3;
    if (v >= NVOX) return;
    int fl = *flag;
    float acc = 0.f;
#pragma unroll
    for (int j = 0; j < 7; j++) {
        int k = q + j * 4;
        if (k < KK) {
            int idx = nidx[k * NVOX + v];
            float m = get_mask(nmask, fl, (long)k * NVOX + v);
            float2 s = ((const float2*)s2)[idx];
            acc += m * (s.x * w[k * 2] + s.y * w[k * 2 + 1]);
        }
    }
    acc += __shfl_xor(acc, 1);
    acc += __shfl_xor(acc, 2);
    if (q == 0) sa[v] = 1.0f / (1.0f + expf(-acc));
}

// ---- gather to points, apply sa, classifier; 2 thr/point split over c ----
__global__ __launch_bounds__(256) void k_final(
        const float* __restrict__ h2, const float* __restrict__ sa,
        const int* __restrict__ p2v, const float* __restrict__ clsw,
        const float* __restrict__ clsb, float* __restrict__ out) {
    __shared__ float w[32 * 20];
    __shared__ float bb[20];
    for (int i = threadIdx.x; i < 640; i += 256) w[i] = clsw[i];
    if (threadIdx.x < 20) bb[threadIdx.x] = clsb[threadIdx.x];
    __syncthreads();
    int t = blockIdx.x * 256 + threadIdx.x;
    int p = t >> 1, ch = t & 1;
    if (p >= NPTS) return;
    int v = p2v[p];
    float s = sa[v];
    float acc[20];
#pragma unroll
    for (int j = 0; j < 20; j++) acc[j] = 0.f;
    const float4* hp = (const float4*)(h2 + (size_t)v * 32) + ch * 4;
#pragma unroll
    for (int q = 0; q < 4; q++) {
        float4 h = hp[q];
        int cb = (ch * 16 + q * 4) * 20;
        float z0 = h.x * s, z1 = h.y * s, z2 = h.z * s, z3 = h.w * s;
#pragma unroll
        for (int j = 0; j < 20; j++)
            acc[j] += z0 * w[cb + j] + z1 * w[cb + 20 + j]
                    + z2 * w[cb + 40 + j] + z3 * w[cb + 60 + j];
    }
#pragma unroll
    for (int j = 0; j < 20; j++) acc[j] += __shfl_xor(acc[j], 1);
    if (ch == 0) {
#pragma unroll
        for (int j = 0; j < 20; j++) out[(size_t)p * 20 + j] = acc[j] + bb[j];
    }
}

extern "C" void kernel_launch(void* const* d_in, const int* in_sizes, int n_in,
                              void* d_out, int out_size, void* d_ws, size_t ws_size,
                              hipStream_t stream) {
    const float* feat = (const float*)d_in[0];
    const float* W1   = (const float*)d_in[1];
    const float* g1   = (const float*)d_in[2];
    const float* b1   = (const float*)d_in[3];
    const float* W2   = (const float*)d_in[4];
    const float* g2   = (const float*)d_in[5];
    const float* b2   = (const float*)d_in[6];
    const float* caw1 = (const float*)d_in[7];
    const float* cab1 = (const float*)d_in[8];
    const float* caw2 = (const float*)d_in[9];
    const float* cab2 = (const float*)d_in[10];
    const float* saW  = (const float*)d_in[11];
    const float* clsw = (const float*)d_in[12];
    const float* clsb = (const float*)d_in[13];
    const int* p2v    = (const int*)d_in[14];
    const int* vb     = (const int*)d_in[15];
    const int* nidx   = (const int*)d_in[16];
    const void* nmask = d_in[17];
    float* out = (float*)d_out;

    int* flag   = (int*)d_ws;
    float* cnt  = (float*)d_ws + 64;              // 60000
    float* vox  = cnt + NVOX;                     // 240000 (raw sums)
    float* bsum = vox + (size_t)NVOX * 4;         // 128
    unsigned int* bmax = (unsigned int*)(bsum + NB * 32);  // 128
    float* bcnt = (float*)(bmax + NB * 32);       // 4
    float* ca   = bcnt + 64;                      // 128 (padded region)
    float* h1   = ca + 128;
    float* h2   = h1 + (size_t)NVOX * 32;
    float* s2   = h2 + (size_t)NVOX * 32;
    float* sa   = s2 + (size_t)NVOX * 2;

    int nzero = NVOX * 5 + NB * 32 * 2 + NB + 64;   // cnt..ca region
    k_init<<<512, 256, 0, stream>>>(cnt, nzero, (const unsigned int*)nmask, flag);
    k_scatter<<<(NPTS + 255) / 256, 256, 0, stream>>>((const float4*)feat, p2v, cnt, vox);
    k_conv1<<<(NVOX + 63) / 64, 256, 0, stream>>>(vox, cnt, W1, g1, b1, nidx, nmask, flag, h1);
    k_conv2<<<(NVOX + 127) / 128, 512, 0, stream>>>(h1, W2, g2, b2, nidx, nmask, flag, h2);
    k_pool<<<512, 256, 0, stream>>>(h2, vb, bsum, bmax, bcnt);
    k_ca<<<1, 64, 0, stream>>>(bsum, bmax, bcnt, caw1, cab1, caw2, cab2, ca);
    k_apply<<<(NVOX * 2 + 255) / 256, 256, 0, stream>>>(h2, ca, vb, s2);
    k_saconv<<<(NVOX * 4 + 255) / 256, 256, 0, stream>>>(s2, saW, nidx, nmask, flag, sa);
    k_final<<<(NPTS * 2 + 255) / 256, 256, 0, stream>>>(h2, sa, p2v, clsw, clsb, out);
}

// Round 8
// 564.326 us; speedup vs baseline: 4.7539x; 1.0000x over previous
//
#include <hip/hip_runtime.h>
#include <hip/hip_bf16.h>

#define NPTS 200000
#define NVOX 60000
#define NB 4
#define KK 27

// ---- mask encoding: 0 = uint8 bool, 1 = int32, 2 = float32 ----
__device__ __forceinline__ float get_mask(const void* nm, int fl, long i) {
    if (fl == 0) return ((const unsigned char*)nm)[i] ? 1.0f : 0.0f;
    if (fl == 1) return ((const int*)nm)[i] ? 1.0f : 0.0f;
    return ((const float*)nm)[i];
}

// ---- init: zero scratch + detect mask encoding (block 0) ----
__global__ void k_init(float* zbase, int nz, const unsigned int* nm, int* flag) {
    for (int i = blockIdx.x * 256 + threadIdx.x; i < nz; i += gridDim.x * 256)
        zbase[i] = 0.f;
    if (blockIdx.x == 0) {
        __shared__ int cntF, cntI;
        if (threadIdx.x == 0) { cntF = 0; cntI = 0; }
        __syncthreads();
        int f = 0, i1 = 0;
        for (int i = threadIdx.x; i < 1024; i += 256) {
            unsigned int v = nm[i];
            if (v == 0x3f800000u) f++;
            if (v == 1u) i1++;
        }
        atomicAdd(&cntF, f); atomicAdd(&cntI, i1);
        __syncthreads();
        if (threadIdx.x == 0)
            *flag = (cntF > 100) ? 2 : ((cntI > 100) ? 1 : 0);
    }
}

// ---- voxelize: scatter-add points into voxels (raw sums; divide fused into conv1) ----
__global__ void k_scatter(const float4* __restrict__ feat, const int* __restrict__ p2v,
                          float* cnt, float* vox) {
    int p = blockIdx.x * 256 + threadIdx.x;
    if (p >= NPTS) return;
    int v = p2v[p];
    float4 f = feat[p];
    atomicAdd(&cnt[v], 1.0f);
    atomicAdd(&vox[v * 4 + 0], f.x);
    atomicAdd(&vox[v * 4 + 1], f.y);
    atomicAdd(&vox[v * 4 + 2], f.z);
    atomicAdd(&vox[v * 4 + 3], f.w);
}

// ---- conv1: Cin=4 -> Cout=32; thread=(voxel, quad of 8 ch); full unroll, no local arrays ----
__global__ __launch_bounds__(256, 4) void k_conv1(
        const float* __restrict__ vox, const float* __restrict__ cnt,
        const float* __restrict__ W1,
        const float* __restrict__ g1, const float* __restrict__ b1,
        const int* __restrict__ nidx, const void* __restrict__ nmask,
        const int* __restrict__ flag, float* __restrict__ h1) {
    int tid = threadIdx.x;
    int vl = tid & 63;
    int q = __builtin_amdgcn_readfirstlane(tid >> 6);   // wave-uniform quad
    int v = blockIdx.x * 64 + vl;
    int vc = v < NVOX ? v : NVOX - 1;
    int fl = *flag;
    float acc[8];
#pragma unroll
    for (int d = 0; d < 8; d++) acc[d] = 0.f;
#pragma unroll
    for (int k = 0; k < KK; k++) {          // FULL unroll: all indices static, no scratch
        int idx = nidx[k * NVOX + vc];
        float m = get_mask(nmask, fl, (long)k * NVOX + vc);
        float4 r = ((const float4*)vox)[idx];
        float mm = m / fmaxf(cnt[idx], 1.0f);   // 0 when masked; fused voxel average
        const float* wk = W1 + k * 128 + q * 8; // wave-uniform -> s_load (W1 fits sL1)
#pragma unroll
        for (int c = 0; c < 4; c++) {
            float rc = (c == 0 ? r.x : c == 1 ? r.y : c == 2 ? r.z : r.w) * mm;
#pragma unroll
            for (int d = 0; d < 8; d++) acc[d] = fmaf(rc, wk[c * 32 + d], acc[d]);
        }
    }
    if (v < NVOX) {
        const float* gp = g1 + q * 8;
        const float* bp = b1 + q * 8;
        float o[8];
#pragma unroll
        for (int d = 0; d < 8; d++) o[d] = fmaxf(acc[d] * gp[d] + bp[d], 0.f);
        float4* op = (float4*)(h1 + (size_t)v * 32 + q * 8);
        op[0] = make_float4(o[0], o[1], o[2], o[3]);
        op[1] = make_float4(o[4], o[5], o[6], o[7]);
    }
}

// ---- conv2: 512 thr = 8 waves (half,kc); 2 voxels per lane -> 128 vox/block ----
// LDS stride 37 (not 33): pushes LDS to 56.8KB so only 2 blocks/CU fit ->
// compiler's occupancy target becomes 4 waves/SIMD -> 128-VGPR budget ->
// the ~110-reg dual-voxel pipeline allocates WITHOUT spilling (round-7 spilled
// at VGPR=64 because 50.7KB LDS allowed 3 blocks -> 6-wave target -> 64-reg cap).
// 37 mod 32 = 5, coprime -> partial-combine stays bank-conflict-free.
__global__ __launch_bounds__(512, 4) void k_conv2(
        const float* __restrict__ h1, const float* __restrict__ W2,
        const float* __restrict__ g2, const float* __restrict__ b2,
        const int* __restrict__ nidx, const void* __restrict__ nmask,
        const int* __restrict__ flag, float* __restrict__ h2) {
    __shared__ float part[3][128][37];
    int tid = threadIdx.x;
    int lane = tid & 63;
    int half = __builtin_amdgcn_readfirstlane((tid >> 6) & 1);  // wave-uniform
    int kc   = __builtin_amdgcn_readfirstlane(tid >> 7);        // wave-uniform
    int vA = blockIdx.x * 128 + lane;
    int vB = vA + 64;
    int vcA = vA < NVOX ? vA : NVOX - 1;
    int vcB = vB < NVOX ? vB : NVOX - 1;
    int fl = *flag;
    int k0 = kc * 7;
    int nk = (kc == 3) ? 6 : 7;   // chunks 7,7,7,6 (uniform)
    const float* Wh = W2 + half * 16;
    float accA[16], accB[16];
#pragma unroll
    for (int d = 0; d < 16; d++) { accA[d] = 0.f; accB[d] = 0.f; }

#pragma unroll
    for (int j = 0; j < 7; j++) {
        if (j < nk) {
            int k = k0 + j;
            int idxA = nidx[k * NVOX + vcA];
            int idxB = nidx[k * NVOX + vcB];
            float mA = get_mask(nmask, fl, (long)k * NVOX + vcA);
            float mB = get_mask(nmask, fl, (long)k * NVOX + vcB);
            // 16 independent dwordx4 loads, all issued up front
            const float4* rpA = (const float4*)(h1 + (size_t)idxA * 32);
            const float4* rpB = (const float4*)(h1 + (size_t)idxB * 32);
            float4 rowA[8], rowB[8];
#pragma unroll
            for (int qq = 0; qq < 8; qq++) rowA[qq] = rpA[qq];
#pragma unroll
            for (int qq = 0; qq < 8; qq++) rowB[qq] = rpB[qq];
            const float* wk = Wh + k * 1024;   // wave-uniform -> s_load
#pragma unroll
            for (int c = 0; c < 32; c++) {
                float4 aqA = rowA[c >> 2], aqB = rowB[c >> 2];
                float rcA = ((c & 3) == 0 ? aqA.x : (c & 3) == 1 ? aqA.y :
                             (c & 3) == 2 ? aqA.z : aqA.w) * mA;
                float rcB = ((c & 3) == 0 ? aqB.x : (c & 3) == 1 ? aqB.y :
                             (c & 3) == 2 ? aqB.z : aqB.w) * mB;
                const float* wc = wk + c * 32;
#pragma unroll
                for (int d = 0; d < 16; d++) {
                    float w = wc[d];
                    accA[d] = fmaf(rcA, w, accA[d]);
                    accB[d] = fmaf(rcB, w, accB[d]);
                }
            }
        }
    }
    if (kc > 0) {
#pragma unroll
        for (int d = 0; d < 16; d++) {
            part[kc - 1][lane][half * 16 + d]      = accA[d];
            part[kc - 1][lane + 64][half * 16 + d] = accB[d];
        }
    }
    __syncthreads();
    if (kc == 0) {
        const float* gp = g2 + half * 16;
        const float* bp = b2 + half * 16;
        if (vA < NVOX) {
            float o[16];
#pragma unroll
            for (int d = 0; d < 16; d++) {
                float s = accA[d] + part[0][lane][half * 16 + d]
                        + part[1][lane][half * 16 + d] + part[2][lane][half * 16 + d];
                o[d] = fmaxf(s * gp[d] + bp[d], 0.f);
            }
            float4* op = (float4*)(h2 + (size_t)vA * 32 + half * 16);
#pragma unroll
            for (int qq = 0; qq < 4; qq++)
                op[qq] = make_float4(o[qq * 4], o[qq * 4 + 1], o[qq * 4 + 2], o[qq * 4 + 3]);
        }
        if (vB < NVOX) {
            float o[16];
#pragma unroll
            for (int d = 0; d < 16; d++) {
                float s = accB[d] + part[0][lane + 64][half * 16 + d]
                        + part[1][lane + 64][half * 16 + d] + part[2][lane + 64][half * 16 + d];
                o[d] = fmaxf(s * gp[d] + bp[d], 0.f);
            }
            float4* op = (float4*)(h2 + (size_t)vB * 32 + half * 16);
#pragma unroll
            for (int qq = 0; qq < 4; qq++)
                op[qq] = make_float4(o[qq * 4], o[qq * 4 + 1], o[qq * 4 + 2], o[qq * 4 + 3]);
        }
    }
}

// ---- per-batch pooling: register accumulation, tiny atomic tail ----
__global__ __launch_bounds__(256) void k_pool(
        const float* __restrict__ h2, const int* __restrict__ vb,
        float* bsum, unsigned int* bmax, float* bcnt) {
    __shared__ float ls[NB * 32];
    __shared__ unsigned int lm[NB * 32];
    __shared__ float lc[NB];
    for (int i = threadIdx.x; i < NB * 32; i += 256) { ls[i] = 0.f; lm[i] = 0u; }
    if (threadIdx.x < NB) lc[threadIdx.x] = 0.f;
    __syncthreads();
    int c = threadIdx.x & 31, slot = threadIdx.x >> 5;
    float s0 = 0, s1 = 0, s2 = 0, s3 = 0, m0 = 0, m1 = 0, m2 = 0, m3 = 0;
    float c0 = 0, c1 = 0, c2 = 0, c3 = 0;
    for (int n = blockIdx.x * 8 + slot; n < NVOX; n += gridDim.x * 8) {
        float vv = h2[(size_t)n * 32 + c];
        int b = vb[n];
        s0 += (b == 0) ? vv : 0.f; m0 = (b == 0) ? fmaxf(m0, vv) : m0;
        s1 += (b == 1) ? vv : 0.f; m1 = (b == 1) ? fmaxf(m1, vv) : m1;
        s2 += (b == 2) ? vv : 0.f; m2 = (b == 2) ? fmaxf(m2, vv) : m2;
        s3 += (b == 3) ? vv : 0.f; m3 = (b == 3) ? fmaxf(m3, vv) : m3;
        if (c == 0) {
            c0 += (b == 0) ? 1.f : 0.f; c1 += (b == 1) ? 1.f : 0.f;
            c2 += (b == 2) ? 1.f : 0.f; c3 += (b == 3) ? 1.f : 0.f;
        }
    }
    atomicAdd(&ls[0 * 32 + c], s0); atomicAdd(&ls[1 * 32 + c], s1);
    atomicAdd(&ls[2 * 32 + c], s2); atomicAdd(&ls[3 * 32 + c], s3);
    atomicMax(&lm[0 * 32 + c], __float_as_uint(m0));  // h2 >= 0
    atomicMax(&lm[1 * 32 + c], __float_as_uint(m1));
    atomicMax(&lm[2 * 32 + c], __float_as_uint(m2));
    atomicMax(&lm[3 * 32 + c], __float_as_uint(m3));
    if (c == 0) {
        atomicAdd(&lc[0], c0); atomicAdd(&lc[1], c1);
        atomicAdd(&lc[2], c2); atomicAdd(&lc[3], c3);
    }
    __syncthreads();
    if (threadIdx.x < NB * 32) {
        atomicAdd(&bsum[threadIdx.x], ls[threadIdx.x]);
        atomicMax(&bmax[threadIdx.x], lm[threadIdx.x]);
    }
    if (threadIdx.x < NB) atomicAdd(&bcnt[threadIdx.x], lc[threadIdx.x]);
}

// ---- channel-attention MLP (tiny, 4 batches) ----
__global__ void k_ca(const float* __restrict__ bsum, const unsigned int* __restrict__ bmax,
                     const float* __restrict__ bcnt,
                     const float* __restrict__ w1, const float* __restrict__ b1,
                     const float* __restrict__ w2, const float* __restrict__ b2,
                     float* ca) {
    int b = threadIdx.x;
    if (b >= NB) return;
    float avg[32], mx[32], o[32];
    float inv = 1.0f / fmaxf(bcnt[b], 1.0f);
#pragma unroll
    for (int c = 0; c < 32; c++) {
        avg[c] = bsum[b * 32 + c] * inv;
        mx[c]  = __uint_as_float(bmax[b * 32 + c]);
        o[c] = 0.f;
    }
#pragma unroll
    for (int pass = 0; pass < 2; pass++) {
        float r[8];
#pragma unroll
        for (int j = 0; j < 8; j++) {
            float s = b1[j];
#pragma unroll
            for (int c = 0; c < 32; c++) s += (pass ? mx[c] : avg[c]) * w1[c * 8 + j];
            r[j] = fmaxf(s, 0.f);
        }
#pragma unroll
        for (int d = 0; d < 32; d++) {
            float s = b2[d];
#pragma unroll
            for (int j = 0; j < 8; j++) s += r[j] * w2[j * 32 + d];
            o[d] += s;
        }
    }
#pragma unroll
    for (int d = 0; d < 32; d++)
        ca[b * 32 + d] = 1.0f / (1.0f + expf(-o[d]));
}

// ---- apply channel attention (in place) + build s2 = [mean_c, max_c]; 2 thr/voxel ----
__global__ void k_apply(float* h2, const float* __restrict__ ca,
                        const int* __restrict__ vb, float* __restrict__ s2) {
    int t = blockIdx.x * 256 + threadIdx.x;
    int v = t >> 1, hf = t & 1;
    if (v >= NVOX) return;
    int b = vb[v];
    float4* hp = (float4*)(h2 + (size_t)v * 32) + hf * 4;
    const float4* cp = (const float4*)(ca + b * 32) + hf * 4;
    float sum = 0.f, mx = 0.f;
#pragma unroll
    for (int q = 0; q < 4; q++) {
        float4 h = hp[q]; float4 c = cp[q];
        h.x *= c.x; h.y *= c.y; h.z *= c.z; h.w *= c.w;
        hp[q] = h;
        sum += h.x + h.y + h.z + h.w;
        mx = fmaxf(mx, fmaxf(fmaxf(h.x, h.y), fmaxf(h.z, h.w)));
    }
    sum += __shfl_xor(sum, 1);
    mx = fmaxf(mx, __shfl_xor(mx, 1));
    if (hf == 0) {
        s2[v * 2 + 0] = sum * (1.0f / 32.0f);
        s2[v * 2 + 1] = mx;
    }
}

// ---- spatial attention: 2-ch sparse conv -> sigmoid; 4 thr/voxel ----
__global__ void k_saconv(const float* __restrict__ s2, const float* __restrict__ saW,
                         const int* __restrict__ nidx, const void* __restrict__ nmask,
                         const int* __restrict__ flag, float* __restrict__ sa) {
    __shared__ float w[KK * 2];
    if (threadIdx.x < KK * 2) w[threadIdx.x] = saW[threadIdx.x];
    __syncthreads();
    int t = blockIdx.x * 256 + threadIdx.x;
    int v = t >> 2, q = t & 3;
    if (v >= NVOX) return;
    int fl = *flag;
    float acc = 0.f;
#pragma unroll
    for (int j = 0; j < 7; j++) {
        int k = q + j * 4;
        if (k < KK) {
            int idx = nidx[k * NVOX + v];
            float m = get_mask(nmask, fl, (long)k * NVOX + v);
            float2 s = ((const float2*)s2)[idx];
            acc += m * (s.x * w[k * 2] + s.y * w[k * 2 + 1]);
        }
    }
    acc += __shfl_xor(acc, 1);
    acc += __shfl_xor(acc, 2);
    if (q == 0) sa[v] = 1.0f / (1.0f + expf(-acc));
}

// ---- gather to points, apply sa, classifier; 2 thr/point split over c ----
__global__ __launch_bounds__(256) void k_final(
        const float* __restrict__ h2, const float* __restrict__ sa,
        const int* __restrict__ p2v, const float* __restrict__ clsw,
        const float* __restrict__ clsb, float* __restrict__ out) {
    __shared__ float w[32 * 20];
    __shared__ float bb[20];
    for (int i = threadIdx.x; i < 640; i += 256) w[i] = clsw[i];
    if (threadIdx.x < 20) bb[threadIdx.x] = clsb[threadIdx.x];
    __syncthreads();
    int t = blockIdx.x * 256 + threadIdx.x;
    int p = t >> 1, ch = t & 1;
    if (p >= NPTS) return;
    int v = p2v[p];
    float s = sa[v];
    float acc[20];
#pragma unroll
    for (int j = 0; j < 20; j++) acc[j] = 0.f;
    const float4* hp = (const float4*)(h2 + (size_t)v * 32) + ch * 4;
#pragma unroll
    for (int q = 0; q < 4; q++) {
        float4 h = hp[q];
        int cb = (ch * 16 + q * 4) * 20;
        float z0 = h.x * s, z1 = h.y * s, z2 = h.z * s, z3 = h.w * s;
#pragma unroll
        for (int j = 0; j < 20; j++)
            acc[j] += z0 * w[cb + j] + z1 * w[cb + 20 + j]
                    + z2 * w[cb + 40 + j] + z3 * w[cb + 60 + j];
    }
#pragma unroll
    for (int j = 0; j < 20; j++) acc[j] += __shfl_xor(acc[j], 1);
    if (ch == 0) {
#pragma unroll
        for (int j = 0; j < 20; j++) out[(size_t)p * 20 + j] = acc[j] + bb[j];
    }
}

extern "C" void kernel_launch(void* const* d_in, const int* in_sizes, int n_in,
                              void* d_out, int out_size, void* d_ws, size_t ws_size,
                              hipStream_t stream) {
    const float* feat = (const float*)d_in[0];
    const float* W1   = (const float*)d_in[1];
    const float* g1   = (const float*)d_in[2];
    const float* b1   = (const float*)d_in[3];
    const float* W2   = (const float*)d_in[4];
    const float* g2   = (const float*)d_in[5];
    const float* b2   = (const float*)d_in[6];
    const float* caw1 = (const float*)d_in[7];
    const float* cab1 = (const float*)d_in[8];
    const float* caw2 = (const float*)d_in[9];
    const float* cab2 = (const float*)d_in[10];
    const float* saW  = (const float*)d_in[11];
    const float* clsw = (const float*)d_in[12];
    const float* clsb = (const float*)d_in[13];
    const int* p2v    = (const int*)d_in[14];
    const int* vb     = (const int*)d_in[15];
    const int* nidx   = (const int*)d_in[16];
    const void* nmask = d_in[17];
    float* out = (float*)d_out;

    int* flag   = (int*)d_ws;
    float* cnt  = (float*)d_ws + 64;              // 60000
    float* vox  = cnt + NVOX;                     // 240000 (raw sums)
    float* bsum = vox + (size_t)NVOX * 4;         // 128
    unsigned int* bmax = (unsigned int*)(bsum + NB * 32);  // 128
    float* bcnt = (float*)(bmax + NB * 32);       // 4
    float* ca   = bcnt + 64;                      // 128 (padded region)
    float* h1   = ca + 128;
    float* h2   = h1 + (size_t)NVOX * 32;
    float* s2   = h2 + (size_t)NVOX * 32;
    float* sa   = s2 + (size_t)NVOX * 2;

    int nzero = NVOX * 5 + NB * 32 * 2 + NB + 64;   // cnt..ca region
    k_init<<<512, 256, 0, stream>>>(cnt, nzero, (const unsigned int*)nmask, flag);
    k_scatter<<<(NPTS + 255) / 256, 256, 0, stream>>>((const float4*)feat, p2v, cnt, vox);
    k_conv1<<<(NVOX + 63) / 64, 256, 0, stream>>>(vox, cnt, W1, g1, b1, nidx, nmask, flag, h1);
    k_conv2<<<(NVOX + 127) / 128, 512, 0, stream>>>(h1, W2, g2, b2, nidx, nmask, flag, h2);
    k_pool<<<512, 256, 0, stream>>>(h2, vb, bsum, bmax, bcnt);
    k_ca<<<1, 64, 0, stream>>>(bsum, bmax, bcnt, caw1, cab1, caw2, cab2, ca);
    k_apply<<<(NVOX * 2 + 255) / 256, 256, 0, stream>>>(h2, ca, vb, s2);
    k_saconv<<<(NVOX * 4 + 255) / 256, 256, 0, stream>>>(s2, saW, nidx, nmask, flag, sa);
    k_final<<<(NPTS * 2 + 255) / 256, 256, 0, stream>>>(h2, sa, p2v, clsw, clsb, out);
}

// Round 9
// 259.445 us; speedup vs baseline: 10.3403x; 2.1751x over previous
//
#include <hip/hip_runtime.h>
#include <hip/hip_bf16.h>

#define NPTS 200000
#define NVOX 60000
#define NB 4
#define KK 27

// ---- mask encoding: 0 = uint8 bool, 1 = int32, 2 = float32 ----
__device__ __forceinline__ float get_mask(const void* nm, int fl, long i) {
    if (fl == 0) return ((const unsigned char*)nm)[i] ? 1.0f : 0.0f;
    if (fl == 1) return ((const int*)nm)[i] ? 1.0f : 0.0f;
    return ((const float*)nm)[i];
}

// ---- init: zero scratch + detect mask encoding (block 0) ----
__global__ void k_init(float* zbase, int nz, const unsigned int* nm, int* flag) {
    for (int i = blockIdx.x * 256 + threadIdx.x; i < nz; i += gridDim.x * 256)
        zbase[i] = 0.f;
    if (blockIdx.x == 0) {
        __shared__ int cntF, cntI;
        if (threadIdx.x == 0) { cntF = 0; cntI = 0; }
        __syncthreads();
        int f = 0, i1 = 0;
        for (int i = threadIdx.x; i < 1024; i += 256) {
            unsigned int v = nm[i];
            if (v == 0x3f800000u) f++;
            if (v == 1u) i1++;
        }
        atomicAdd(&cntF, f); atomicAdd(&cntI, i1);
        __syncthreads();
        if (threadIdx.x == 0)
            *flag = (cntF > 100) ? 2 : ((cntI > 100) ? 1 : 0);
    }
}

// ---- voxelize: scatter-add points into voxels (raw sums; divide fused into conv1) ----
__global__ void k_scatter(const float4* __restrict__ feat, const int* __restrict__ p2v,
                          float* cnt, float* vox) {
    int p = blockIdx.x * 256 + threadIdx.x;
    if (p >= NPTS) return;
    int v = p2v[p];
    float4 f = feat[p];
    atomicAdd(&cnt[v], 1.0f);
    atomicAdd(&vox[v * 4 + 0], f.x);
    atomicAdd(&vox[v * 4 + 1], f.y);
    atomicAdd(&vox[v * 4 + 2], f.z);
    atomicAdd(&vox[v * 4 + 3], f.w);
}

// ---- conv1: Cin=4 -> Cout=32; thread=(voxel, quad of 8 ch); non-unrolled k loop ----
__global__ __launch_bounds__(256, 4) void k_conv1(
        const float* __restrict__ vox, const float* __restrict__ cnt,
        const float* __restrict__ W1,
        const float* __restrict__ g1, const float* __restrict__ b1,
        const int* __restrict__ nidx, const void* __restrict__ nmask,
        const int* __restrict__ flag, float* __restrict__ h1) {
    int tid = threadIdx.x;
    int vl = tid & 63;
    int q = __builtin_amdgcn_readfirstlane(tid >> 6);   // wave-uniform quad
    int v = blockIdx.x * 64 + vl;
    int vc = v < NVOX ? v : NVOX - 1;
    int fl = *flag;
    float acc[8];
#pragma unroll
    for (int d = 0; d < 8; d++) acc[d] = 0.f;
#pragma unroll 1
    for (int k = 0; k < KK; k++) {          // no unroll: bounded load hoisting
        int idx = nidx[k * NVOX + vc];
        float m = get_mask(nmask, fl, (long)k * NVOX + vc);
        float4 r = ((const float4*)vox)[idx];
        float mm = m / fmaxf(cnt[idx], 1.0f);   // 0 when masked; fused voxel average
        const float* wk = W1 + k * 128 + q * 8; // wave-uniform -> s_load (W1 fits sL1)
#pragma unroll
        for (int c = 0; c < 4; c++) {
            float rc = (c == 0 ? r.x : c == 1 ? r.y : c == 2 ? r.z : r.w) * mm;
#pragma unroll
            for (int d = 0; d < 8; d++) acc[d] = fmaf(rc, wk[c * 32 + d], acc[d]);
        }
    }
    if (v < NVOX) {
        const float* gp = g1 + q * 8;
        const float* bp = b1 + q * 8;
        float o[8];
#pragma unroll
        for (int d = 0; d < 8; d++) o[d] = fmaxf(acc[d] * gp[d] + bp[d], 0.f);
        float4* op = (float4*)(h1 + (size_t)v * 32 + q * 8);
        op[0] = make_float4(o[0], o[1], o[2], o[3]);
        op[1] = make_float4(o[4], o[5], o[6], o[7]);
    }
}

// ---- conv2: 512 thr = 8 waves (half,kc); 2 voxels/lane; k-loop NOT unrolled ----
// Spill root-cause (r6-r8): full j-unroll let the scheduler hoist 7x16 gathers
// -> pressure ~450 regs -> clamp@64 + massive scratch. Fix: unroll 1 (one k's
// loads in flight), c-split into two halves (live rows 2x16 not 2x32), and
// __launch_bounds__(512,2) -> 256-VGPR cap. Static worst case ~80 regs.
__global__ __launch_bounds__(512, 2) void k_conv2(
        const float* __restrict__ h1, const float* __restrict__ W2,
        const float* __restrict__ g2, const float* __restrict__ b2,
        const int* __restrict__ nidx, const void* __restrict__ nmask,
        const int* __restrict__ flag, float* __restrict__ h2) {
    __shared__ float part[3][128][37];
    int tid = threadIdx.x;
    int lane = tid & 63;
    int half = __builtin_amdgcn_readfirstlane((tid >> 6) & 1);  // wave-uniform
    int kc   = __builtin_amdgcn_readfirstlane(tid >> 7);        // wave-uniform
    int vA = blockIdx.x * 128 + lane;
    int vB = vA + 64;
    int vcA = vA < NVOX ? vA : NVOX - 1;
    int vcB = vB < NVOX ? vB : NVOX - 1;
    int fl = *flag;
    int k0 = kc * 7;
    int k1 = (kc == 3) ? KK : k0 + 7;   // chunks 7,7,7,6 (uniform)
    const float* Wh = W2 + half * 16;
    float accA[16], accB[16];
#pragma unroll
    for (int d = 0; d < 16; d++) { accA[d] = 0.f; accB[d] = 0.f; }

#pragma unroll 1
    for (int k = k0; k < k1; ++k) {
        int idxA = nidx[k * NVOX + vcA];
        int idxB = nidx[k * NVOX + vcB];
        float mA = get_mask(nmask, fl, (long)k * NVOX + vcA);
        float mB = get_mask(nmask, fl, (long)k * NVOX + vcB);
        const float4* rpA = (const float4*)(h1 + (size_t)idxA * 32);
        const float4* rpB = (const float4*)(h1 + (size_t)idxB * 32);
        const float* wk = Wh + k * 1024;   // wave-uniform -> s_load stream
        // ---- first c-half: input channels 0..15 (quads 0..3) ----
        {
            float4 rA[4] = { rpA[0], rpA[1], rpA[2], rpA[3] };
            float4 rB[4] = { rpB[0], rpB[1], rpB[2], rpB[3] };
#pragma unroll
            for (int c = 0; c < 16; c++) {
                float4 aqA = rA[c >> 2], aqB = rB[c >> 2];
                float rcA = ((c & 3) == 0 ? aqA.x : (c & 3) == 1 ? aqA.y :
                             (c & 3) == 2 ? aqA.z : aqA.w) * mA;
                float rcB = ((c & 3) == 0 ? aqB.x : (c & 3) == 1 ? aqB.y :
                             (c & 3) == 2 ? aqB.z : aqB.w) * mB;
                const float* wc = wk + c * 32;
#pragma unroll
                for (int d = 0; d < 16; d++) {
                    float w = wc[d];
                    accA[d] = fmaf(rcA, w, accA[d]);
                    accB[d] = fmaf(rcB, w, accB[d]);
                }
            }
        }
        // ---- second c-half: input channels 16..31 (quads 4..7) ----
        {
            float4 rA[4] = { rpA[4], rpA[5], rpA[6], rpA[7] };
            float4 rB[4] = { rpB[4], rpB[5], rpB[6], rpB[7] };
#pragma unroll
            for (int c = 16; c < 32; c++) {
                float4 aqA = rA[(c >> 2) - 4], aqB = rB[(c >> 2) - 4];
                float rcA = ((c & 3) == 0 ? aqA.x : (c & 3) == 1 ? aqA.y :
                             (c & 3) == 2 ? aqA.z : aqA.w) * mA;
                float rcB = ((c & 3) == 0 ? aqB.x : (c & 3) == 1 ? aqB.y :
                             (c & 3) == 2 ? aqB.z : aqB.w) * mB;
                const float* wc = wk + c * 32;
#pragma unroll
                for (int d = 0; d < 16; d++) {
                    float w = wc[d];
                    accA[d] = fmaf(rcA, w, accA[d]);
                    accB[d] = fmaf(rcB, w, accB[d]);
                }
            }
        }
    }
    if (kc > 0) {
#pragma unroll
        for (int d = 0; d < 16; d++) {
            part[kc - 1][lane][half * 16 + d]      = accA[d];
            part[kc - 1][lane + 64][half * 16 + d] = accB[d];
        }
    }
    __syncthreads();
    if (kc == 0) {
        const float* gp = g2 + half * 16;
        const float* bp = b2 + half * 16;
        if (vA < NVOX) {
            float o[16];
#pragma unroll
            for (int d = 0; d < 16; d++) {
                float s = accA[d] + part[0][lane][half * 16 + d]
                        + part[1][lane][half * 16 + d] + part[2][lane][half * 16 + d];
                o[d] = fmaxf(s * gp[d] + bp[d], 0.f);
            }
            float4* op = (float4*)(h2 + (size_t)vA * 32 + half * 16);
#pragma unroll
            for (int qq = 0; qq < 4; qq++)
                op[qq] = make_float4(o[qq * 4], o[qq * 4 + 1], o[qq * 4 + 2], o[qq * 4 + 3]);
        }
        if (vB < NVOX) {
            float o[16];
#pragma unroll
            for (int d = 0; d < 16; d++) {
                float s = accB[d] + part[0][lane + 64][half * 16 + d]
                        + part[1][lane + 64][half * 16 + d] + part[2][lane + 64][half * 16 + d];
                o[d] = fmaxf(s * gp[d] + bp[d], 0.f);
            }
            float4* op = (float4*)(h2 + (size_t)vB * 32 + half * 16);
#pragma unroll
            for (int qq = 0; qq < 4; qq++)
                op[qq] = make_float4(o[qq * 4], o[qq * 4 + 1], o[qq * 4 + 2], o[qq * 4 + 3]);
        }
    }
}

// ---- per-batch pooling: register accumulation, tiny atomic tail ----
__global__ __launch_bounds__(256) void k_pool(
        const float* __restrict__ h2, const int* __restrict__ vb,
        float* bsum, unsigned int* bmax, float* bcnt) {
    __shared__ float ls[NB * 32];
    __shared__ unsigned int lm[NB * 32];
    __shared__ float lc[NB];
    for (int i = threadIdx.x; i < NB * 32; i += 256) { ls[i] = 0.f; lm[i] = 0u; }
    if (threadIdx.x < NB) lc[threadIdx.x] = 0.f;
    __syncthreads();
    int c = threadIdx.x & 31, slot = threadIdx.x >> 5;
    float s0 = 0, s1 = 0, s2 = 0, s3 = 0, m0 = 0, m1 = 0, m2 = 0, m3 = 0;
    float c0 = 0, c1 = 0, c2 = 0, c3 = 0;
    for (int n = blockIdx.x * 8 + slot; n < NVOX; n += gridDim.x * 8) {
        float vv = h2[(size_t)n * 32 + c];
        int b = vb[n];
        s0 += (b == 0) ? vv : 0.f; m0 = (b == 0) ? fmaxf(m0, vv) : m0;
        s1 += (b == 1) ? vv : 0.f; m1 = (b == 1) ? fmaxf(m1, vv) : m1;
        s2 += (b == 2) ? vv : 0.f; m2 = (b == 2) ? fmaxf(m2, vv) : m2;
        s3 += (b == 3) ? vv : 0.f; m3 = (b == 3) ? fmaxf(m3, vv) : m3;
        if (c == 0) {
            c0 += (b == 0) ? 1.f : 0.f; c1 += (b == 1) ? 1.f : 0.f;
            c2 += (b == 2) ? 1.f : 0.f; c3 += (b == 3) ? 1.f : 0.f;
        }
    }
    atomicAdd(&ls[0 * 32 + c], s0); atomicAdd(&ls[1 * 32 + c], s1);
    atomicAdd(&ls[2 * 32 + c], s2); atomicAdd(&ls[3 * 32 + c], s3);
    atomicMax(&lm[0 * 32 + c], __float_as_uint(m0));  // h2 >= 0
    atomicMax(&lm[1 * 32 + c], __float_as_uint(m1));
    atomicMax(&lm[2 * 32 + c], __float_as_uint(m2));
    atomicMax(&lm[3 * 32 + c], __float_as_uint(m3));
    if (c == 0) {
        atomicAdd(&lc[0], c0); atomicAdd(&lc[1], c1);
        atomicAdd(&lc[2], c2); atomicAdd(&lc[3], c3);
    }
    __syncthreads();
    if (threadIdx.x < NB * 32) {
        atomicAdd(&bsum[threadIdx.x], ls[threadIdx.x]);
        atomicMax(&bmax[threadIdx.x], lm[threadIdx.x]);
    }
    if (threadIdx.x < NB) atomicAdd(&bcnt[threadIdx.x], lc[threadIdx.x]);
}

// ---- channel-attention MLP (tiny, 4 batches) ----
__global__ void k_ca(const float* __restrict__ bsum, const unsigned int* __restrict__ bmax,
                     const float* __restrict__ bcnt,
                     const float* __restrict__ w1, const float* __restrict__ b1,
                     const float* __restrict__ w2, const float* __restrict__ b2,
                     float* ca) {
    int b = threadIdx.x;
    if (b >= NB) return;
    float avg[32], mx[32], o[32];
    float inv = 1.0f / fmaxf(bcnt[b], 1.0f);
#pragma unroll
    for (int c = 0; c < 32; c++) {
        avg[c] = bsum[b * 32 + c] * inv;
        mx[c]  = __uint_as_float(bmax[b * 32 + c]);
        o[c] = 0.f;
    }
#pragma unroll
    for (int pass = 0; pass < 2; pass++) {
        float r[8];
#pragma unroll
        for (int j = 0; j < 8; j++) {
            float s = b1[j];
#pragma unroll
            for (int c = 0; c < 32; c++) s += (pass ? mx[c] : avg[c]) * w1[c * 8 + j];
            r[j] = fmaxf(s, 0.f);
        }
#pragma unroll
        for (int d = 0; d < 32; d++) {
            float s = b2[d];
#pragma unroll
            for (int j = 0; j < 8; j++) s += r[j] * w2[j * 32 + d];
            o[d] += s;
        }
    }
#pragma unroll
    for (int d = 0; d < 32; d++)
        ca[b * 32 + d] = 1.0f / (1.0f + expf(-o[d]));
}

// ---- apply channel attention (in place) + build s2 = [mean_c, max_c]; 2 thr/voxel ----
__global__ void k_apply(float* h2, const float* __restrict__ ca,
                        const int* __restrict__ vb, float* __restrict__ s2) {
    int t = blockIdx.x * 256 + threadIdx.x;
    int v = t >> 1, hf = t & 1;
    if (v >= NVOX) return;
    int b = vb[v];
    float4* hp = (float4*)(h2 + (size_t)v * 32) + hf * 4;
    const float4* cp = (const float4*)(ca + b * 32) + hf * 4;
    float sum = 0.f, mx = 0.f;
#pragma unroll
    for (int q = 0; q < 4; q++) {
        float4 h = hp[q]; float4 c = cp[q];
        h.x *= c.x; h.y *= c.y; h.z *= c.z; h.w *= c.w;
        hp[q] = h;
        sum += h.x + h.y + h.z + h.w;
        mx = fmaxf(mx, fmaxf(fmaxf(h.x, h.y), fmaxf(h.z, h.w)));
    }
    sum += __shfl_xor(sum, 1);
    mx = fmaxf(mx, __shfl_xor(mx, 1));
    if (hf == 0) {
        s2[v * 2 + 0] = sum * (1.0f / 32.0f);
        s2[v * 2 + 1] = mx;
    }
}

// ---- spatial attention: 2-ch sparse conv -> sigmoid; 4 thr/voxel ----
__global__ void k_saconv(const float* __restrict__ s2, const float* __restrict__ saW,
                         const int* __restrict__ nidx, const void* __restrict__ nmask,
                         const int* __restrict__ flag, float* __restrict__ sa) {
    __shared__ float w[KK * 2];
    if (threadIdx.x < KK * 2) w[threadIdx.x] = saW[threadIdx.x];
    __syncthreads();
    int t = blockIdx.x * 256 + threadIdx.x;
    int v = t >> 2, q = t & 3;
    if (v >= NVOX) return;
    int fl = *flag;
    float acc = 0.f;
#pragma unroll
    for (int j = 0; j < 7; j++) {
        int k = q + j * 4;
        if (k < KK) {
            int idx = nidx[k * NVOX + v];
            float m = get_mask(nmask, fl, (long)k * NVOX + v);
            float2 s = ((const float2*)s2)[idx];
            acc += m * (s.x * w[k * 2] + s.y * w[k * 2 + 1]);
        }
    }
    acc += __shfl_xor(acc, 1);
    acc += __shfl_xor(acc, 2);
    if (q == 0) sa[v] = 1.0f / (1.0f + expf(-acc));
}

// ---- gather to points, apply sa, classifier; 2 thr/point split over c ----
__global__ __launch_bounds__(256) void k_final(
        const float* __restrict__ h2, const float* __restrict__ sa,
        const int* __restrict__ p2v, const float* __restrict__ clsw,
        const float* __restrict__ clsb, float* __restrict__ out) {
    __shared__ float w[32 * 20];
    __shared__ float bb[20];
    for (int i = threadIdx.x; i < 640; i += 256) w[i] = clsw[i];
    if (threadIdx.x < 20) bb[threadIdx.x] = clsb[threadIdx.x];
    __syncthreads();
    int t = blockIdx.x * 256 + threadIdx.x;
    int p = t >> 1, ch = t & 1;
    if (p >= NPTS) return;
    int v = p2v[p];
    float s = sa[v];
    float acc[20];
#pragma unroll
    for (int j = 0; j < 20; j++) acc[j] = 0.f;
    const float4* hp = (const float4*)(h2 + (size_t)v * 32) + ch * 4;
#pragma unroll
    for (int q = 0; q < 4; q++) {
        float4 h = hp[q];
        int cb = (ch * 16 + q * 4) * 20;
        float z0 = h.x * s, z1 = h.y * s, z2 = h.z * s, z3 = h.w * s;
#pragma unroll
        for (int j = 0; j < 20; j++)
            acc[j] += z0 * w[cb + j] + z1 * w[cb + 20 + j]
                    + z2 * w[cb + 40 + j] + z3 * w[cb + 60 + j];
    }
#pragma unroll
    for (int j = 0; j < 20; j++) acc[j] += __shfl_xor(acc[j], 1);
    if (ch == 0) {
#pragma unroll
        for (int j = 0; j < 20; j++) out[(size_t)p * 20 + j] = acc[j] + bb[j];
    }
}

extern "C" void kernel_launch(void* const* d_in, const int* in_sizes, int n_in,
                              void* d_out, int out_size, void* d_ws, size_t ws_size,
                              hipStream_t stream) {
    const float* feat = (const float*)d_in[0];
    const float* W1   = (const float*)d_in[1];
    const float* g1   = (const float*)d_in[2];
    const float* b1   = (const float*)d_in[3];
    const float* W2   = (const float*)d_in[4];
    const float* g2   = (const float*)d_in[5];
    const float* b2   = (const float*)d_in[6];
    const float* caw1 = (const float*)d_in[7];
    const float* cab1 = (const float*)d_in[8];
    const float* caw2 = (const float*)d_in[9];
    const float* cab2 = (const float*)d_in[10];
    const float* saW  = (const float*)d_in[11];
    const float* clsw = (const float*)d_in[12];
    const float* clsb = (const float*)d_in[13];
    const int* p2v    = (const int*)d_in[14];
    const int* vb     = (const int*)d_in[15];
    const int* nidx   = (const int*)d_in[16];
    const void* nmask = d_in[17];
    float* out = (float*)d_out;

    int* flag   = (int*)d_ws;
    float* cnt  = (float*)d_ws + 64;              // 60000
    float* vox  = cnt + NVOX;                     // 240000 (raw sums)
    float* bsum = vox + (size_t)NVOX * 4;         // 128
    unsigned int* bmax = (unsigned int*)(bsum + NB * 32);  // 128
    float* bcnt = (float*)(bmax + NB * 32);       // 4
    float* ca   = bcnt + 64;                      // 128 (padded region)
    float* h1   = ca + 128;
    float* h2   = h1 + (size_t)NVOX * 32;
    float* s2   = h2 + (size_t)NVOX * 32;
    float* sa   = s2 + (size_t)NVOX * 2;

    int nzero = NVOX * 5 + NB * 32 * 2 + NB + 64;   // cnt..ca region
    k_init<<<512, 256, 0, stream>>>(cnt, nzero, (const unsigned int*)nmask, flag);
    k_scatter<<<(NPTS + 255) / 256, 256, 0, stream>>>((const float4*)feat, p2v, cnt, vox);
    k_conv1<<<(NVOX + 63) / 64, 256, 0, stream>>>(vox, cnt, W1, g1, b1, nidx, nmask, flag, h1);
    k_conv2<<<(NVOX + 127) / 128, 512, 0, stream>>>(h1, W2, g2, b2, nidx, nmask, flag, h2);
    k_pool<<<512, 256, 0, stream>>>(h2, vb, bsum, bmax, bcnt);
    k_ca<<<1, 64, 0, stream>>>(bsum, bmax, bcnt, caw1, cab1, caw2, cab2, ca);
    k_apply<<<(NVOX * 2 + 255) / 256, 256, 0, stream>>>(h2, ca, vb, s2);
    k_saconv<<<(NVOX * 4 + 255) / 256, 256, 0, stream>>>(s2, saW, nidx, nmask, flag, sa);
    k_final<<<(NPTS * 2 + 255) / 256, 256, 0, stream>>>(h2, sa, p2v, clsw, clsb, out);
}

// Round 10
// 218.352 us; speedup vs baseline: 12.2864x; 1.1882x over previous
//
#include <hip/hip_runtime.h>
#include <hip/hip_bf16.h>

#define NPTS 200000
#define NVOX 60000
#define NB 4
#define KK 27

// ---- mask encoding: 0 = uint8 bool, 1 = int32, 2 = float32 ----
__device__ __forceinline__ float get_mask(const void* nm, int fl, long i) {
    if (fl == 0) return ((const unsigned char*)nm)[i] ? 1.0f : 0.0f;
    if (fl == 1) return ((const int*)nm)[i] ? 1.0f : 0.0f;
    return ((const float*)nm)[i];
}

// ---- init: zero scratch + detect mask encoding (block 0) ----
__global__ void k_init(float* zbase, int nz, const unsigned int* nm, int* flag) {
    for (int i = blockIdx.x * 256 + threadIdx.x; i < nz; i += gridDim.x * 256)
        zbase[i] = 0.f;
    if (blockIdx.x == 0) {
        __shared__ int cntF, cntI;
        if (threadIdx.x == 0) { cntF = 0; cntI = 0; }
        __syncthreads();
        int f = 0, i1 = 0;
        for (int i = threadIdx.x; i < 1024; i += 256) {
            unsigned int v = nm[i];
            if (v == 0x3f800000u) f++;
            if (v == 1u) i1++;
        }
        atomicAdd(&cntF, f); atomicAdd(&cntI, i1);
        __syncthreads();
        if (threadIdx.x == 0)
            *flag = (cntF > 100) ? 2 : ((cntI > 100) ? 1 : 0);
    }
}

// ---- voxelize: scatter-add points into voxels ----
__global__ void k_scatter(const float4* __restrict__ feat, const int* __restrict__ p2v,
                          float* cnt, float* vox) {
    int p = blockIdx.x * 256 + threadIdx.x;
    if (p >= NPTS) return;
    int v = p2v[p];
    float4 f = feat[p];
    atomicAdd(&cnt[v], 1.0f);
    atomicAdd(&vox[v * 4 + 0], f.x);
    atomicAdd(&vox[v * 4 + 1], f.y);
    atomicAdd(&vox[v * 4 + 2], f.z);
    atomicAdd(&vox[v * 4 + 3], f.w);
}

// ---- voxdiv restored: coalesced divide (kills per-k scattered cnt[] gathers in conv1) ----
__global__ void k_voxdiv(float* vox, const float* __restrict__ cnt) {
    int n = blockIdx.x * 256 + threadIdx.x;
    if (n >= NVOX) return;
    float inv = 1.0f / fmaxf(cnt[n], 1.0f);
    float4* vp = (float4*)(vox + n * 4);
    float4 v = *vp;
    v.x *= inv; v.y *= inv; v.z *= inv; v.w *= inv;
    *vp = v;
}

// ---- conv1: Cin=4 -> Cout=32; 256 thr = 64 vox x 4 kc-waves; all 32 d per lane ----
// No duplicate gathers: each (k,voxel) row fetched exactly once.
__global__ __launch_bounds__(256) void k_conv1(
        const float* __restrict__ vox, const float* __restrict__ W1,
        const float* __restrict__ g1, const float* __restrict__ b1,
        const int* __restrict__ nidx, const void* __restrict__ nmask,
        const int* __restrict__ flag, float* __restrict__ h1) {
    __shared__ float part[3][64][33];
    int tid = threadIdx.x;
    int lane = tid & 63;
    int kc = __builtin_amdgcn_readfirstlane(tid >> 6);   // wave-uniform chunk
    int v = blockIdx.x * 64 + lane;
    int vc = v < NVOX ? v : NVOX - 1;
    int fl = *flag;
    int k0 = kc * 7;
    int k1 = (kc == 3) ? KK : k0 + 7;   // 7,7,7,6
    float acc[32];
#pragma unroll
    for (int d = 0; d < 32; d++) acc[d] = 0.f;
#pragma unroll 1
    for (int k = k0; k < k1; ++k) {
        int idx = nidx[k * NVOX + vc];
        float m = get_mask(nmask, fl, (long)k * NVOX + vc);
        float4 r = ((const float4*)vox)[idx];
        const float* wk = W1 + k * 128;   // wave-uniform -> s_load
#pragma unroll
        for (int c = 0; c < 4; c++) {
            float rc = (c == 0 ? r.x : c == 1 ? r.y : c == 2 ? r.z : r.w) * m;
            const float* wc = wk + c * 32;
#pragma unroll
            for (int d = 0; d < 32; d++) acc[d] = fmaf(rc, wc[d], acc[d]);
        }
    }
    if (kc > 0) {
#pragma unroll
        for (int d = 0; d < 32; d++) part[kc - 1][lane][d] = acc[d];
    }
    __syncthreads();
    if (kc == 0 && v < NVOX) {
        float o[32];
#pragma unroll
        for (int d = 0; d < 32; d++) {
            float s = acc[d] + part[0][lane][d] + part[1][lane][d] + part[2][lane][d];
            o[d] = fmaxf(s * g1[d] + b1[d], 0.f);
        }
        float4* op = (float4*)(h1 + (size_t)v * 32);
#pragma unroll
        for (int qq = 0; qq < 8; qq++)
            op[qq] = make_float4(o[qq * 4], o[qq * 4 + 1], o[qq * 4 + 2], o[qq * 4 + 3]);
    }
}

// ---- conv2: 512 thr = 8 waves (vhalf, kc); 1 voxel/lane, all 32 d per lane ----
// Dedup: each h1 row fetched ONCE per (k,voxel) (r9's half-waves fetched twice).
// Requests:FMA now 1:1. Live regs: acc32 + rows16(phase) + addr ~= 58 < 64 cap.
__global__ __launch_bounds__(512) void k_conv2(
        const float* __restrict__ h1, const float* __restrict__ W2,
        const float* __restrict__ g2, const float* __restrict__ b2,
        const int* __restrict__ nidx, const void* __restrict__ nmask,
        const int* __restrict__ flag, float* __restrict__ h2) {
    __shared__ float part[3][128][33];   // 52.3KB -> 3 blocks/CU
    int tid = threadIdx.x;
    int lane = tid & 63;
    int wav = tid >> 6;
    int vhalf = __builtin_amdgcn_readfirstlane(wav & 1);   // wave-uniform
    int kc    = __builtin_amdgcn_readfirstlane(wav >> 1);  // wave-uniform
    int v = blockIdx.x * 128 + vhalf * 64 + lane;
    int vc = v < NVOX ? v : NVOX - 1;
    int fl = *flag;
    int k0 = kc * 7;
    int k1 = (kc == 3) ? KK : k0 + 7;   // 7,7,7,6
    float acc[32];
#pragma unroll
    for (int d = 0; d < 32; d++) acc[d] = 0.f;

#pragma unroll 1
    for (int k = k0; k < k1; ++k) {
        int idx = nidx[k * NVOX + vc];
        float m = get_mask(nmask, fl, (long)k * NVOX + vc);
        const float4* rp = (const float4*)(h1 + (size_t)idx * 32);
        const float* wk = W2 + k * 1024;   // wave-uniform -> s_load
        // phase 1: input channels 0..15
        {
            float4 rq[4] = { rp[0], rp[1], rp[2], rp[3] };
#pragma unroll
            for (int c = 0; c < 16; c++) {
                float4 aq = rq[c >> 2];
                float rc = ((c & 3) == 0 ? aq.x : (c & 3) == 1 ? aq.y :
                            (c & 3) == 2 ? aq.z : aq.w) * m;
                const float* wc = wk + c * 32;
#pragma unroll
                for (int d = 0; d < 32; d++) acc[d] = fmaf(rc, wc[d], acc[d]);
            }
        }
        // phase 2: input channels 16..31
        {
            float4 rq[4] = { rp[4], rp[5], rp[6], rp[7] };
#pragma unroll
            for (int c = 16; c < 32; c++) {
                float4 aq = rq[(c >> 2) - 4];
                float rc = ((c & 3) == 0 ? aq.x : (c & 3) == 1 ? aq.y :
                            (c & 3) == 2 ? aq.z : aq.w) * m;
                const float* wc = wk + c * 32;
#pragma unroll
                for (int d = 0; d < 32; d++) acc[d] = fmaf(rc, wc[d], acc[d]);
            }
        }
    }
    int row = vhalf * 64 + lane;
    if (kc > 0) {
#pragma unroll
        for (int d = 0; d < 32; d++) part[kc - 1][row][d] = acc[d];
    }
    __syncthreads();
    if (kc == 0 && v < NVOX) {
        float o[32];
#pragma unroll
        for (int d = 0; d < 32; d++) {
            float s = acc[d] + part[0][row][d] + part[1][row][d] + part[2][row][d];
            o[d] = fmaxf(s * g2[d] + b2[d], 0.f);
        }
        float4* op = (float4*)(h2 + (size_t)v * 32);
#pragma unroll
        for (int qq = 0; qq < 8; qq++)
            op[qq] = make_float4(o[qq * 4], o[qq * 4 + 1], o[qq * 4 + 2], o[qq * 4 + 3]);
    }
}

// ---- per-batch pooling: register accumulation, tiny atomic tail ----
__global__ __launch_bounds__(256) void k_pool(
        const float* __restrict__ h2, const int* __restrict__ vb,
        float* bsum, unsigned int* bmax, float* bcnt) {
    __shared__ float ls[NB * 32];
    __shared__ unsigned int lm[NB * 32];
    __shared__ float lc[NB];
    for (int i = threadIdx.x; i < NB * 32; i += 256) { ls[i] = 0.f; lm[i] = 0u; }
    if (threadIdx.x < NB) lc[threadIdx.x] = 0.f;
    __syncthreads();
    int c = threadIdx.x & 31, slot = threadIdx.x >> 5;
    float s0 = 0, s1 = 0, s2 = 0, s3 = 0, m0 = 0, m1 = 0, m2 = 0, m3 = 0;
    float c0 = 0, c1 = 0, c2 = 0, c3 = 0;
    for (int n = blockIdx.x * 8 + slot; n < NVOX; n += gridDim.x * 8) {
        float vv = h2[(size_t)n * 32 + c];
        int b = vb[n];
        s0 += (b == 0) ? vv : 0.f; m0 = (b == 0) ? fmaxf(m0, vv) : m0;
        s1 += (b == 1) ? vv : 0.f; m1 = (b == 1) ? fmaxf(m1, vv) : m1;
        s2 += (b == 2) ? vv : 0.f; m2 = (b == 2) ? fmaxf(m2, vv) : m2;
        s3 += (b == 3) ? vv : 0.f; m3 = (b == 3) ? fmaxf(m3, vv) : m3;
        if (c == 0) {
            c0 += (b == 0) ? 1.f : 0.f; c1 += (b == 1) ? 1.f : 0.f;
            c2 += (b == 2) ? 1.f : 0.f; c3 += (b == 3) ? 1.f : 0.f;
        }
    }
    atomicAdd(&ls[0 * 32 + c], s0); atomicAdd(&ls[1 * 32 + c], s1);
    atomicAdd(&ls[2 * 32 + c], s2); atomicAdd(&ls[3 * 32 + c], s3);
    atomicMax(&lm[0 * 32 + c], __float_as_uint(m0));  // h2 >= 0
    atomicMax(&lm[1 * 32 + c], __float_as_uint(m1));
    atomicMax(&lm[2 * 32 + c], __float_as_uint(m2));
    atomicMax(&lm[3 * 32 + c], __float_as_uint(m3));
    if (c == 0) {
        atomicAdd(&lc[0], c0); atomicAdd(&lc[1], c1);
        atomicAdd(&lc[2], c2); atomicAdd(&lc[3], c3);
    }
    __syncthreads();
    if (threadIdx.x < NB * 32) {
        atomicAdd(&bsum[threadIdx.x], ls[threadIdx.x]);
        atomicMax(&bmax[threadIdx.x], lm[threadIdx.x]);
    }
    if (threadIdx.x < NB) atomicAdd(&bcnt[threadIdx.x], lc[threadIdx.x]);
}

// ---- channel-attention MLP (tiny, 4 batches) ----
__global__ void k_ca(const float* __restrict__ bsum, const unsigned int* __restrict__ bmax,
                     const float* __restrict__ bcnt,
                     const float* __restrict__ w1, const float* __restrict__ b1,
                     const float* __restrict__ w2, const float* __restrict__ b2,
                     float* ca) {
    int b = threadIdx.x;
    if (b >= NB) return;
    float avg[32], mx[32], o[32];
    float inv = 1.0f / fmaxf(bcnt[b], 1.0f);
#pragma unroll
    for (int c = 0; c < 32; c++) {
        avg[c] = bsum[b * 32 + c] * inv;
        mx[c]  = __uint_as_float(bmax[b * 32 + c]);
        o[c] = 0.f;
    }
#pragma unroll
    for (int pass = 0; pass < 2; pass++) {
        float r[8];
#pragma unroll
        for (int j = 0; j < 8; j++) {
            float s = b1[j];
#pragma unroll
            for (int c = 0; c < 32; c++) s += (pass ? mx[c] : avg[c]) * w1[c * 8 + j];
            r[j] = fmaxf(s, 0.f);
        }
#pragma unroll
        for (int d = 0; d < 32; d++) {
            float s = b2[d];
#pragma unroll
            for (int j = 0; j < 8; j++) s += r[j] * w2[j * 32 + d];
            o[d] += s;
        }
    }
#pragma unroll
    for (int d = 0; d < 32; d++)
        ca[b * 32 + d] = 1.0f / (1.0f + expf(-o[d]));
}

// ---- apply channel attention (in place) + build s2 = [mean_c, max_c]; 2 thr/voxel ----
__global__ void k_apply(float* h2, const float* __restrict__ ca,
                        const int* __restrict__ vb, float* __restrict__ s2) {
    int t = blockIdx.x * 256 + threadIdx.x;
    int v = t >> 1, hf = t & 1;
    if (v >= NVOX) return;
    int b = vb[v];
    float4* hp = (float4*)(h2 + (size_t)v * 32) + hf * 4;
    const float4* cp = (const float4*)(ca + b * 32) + hf * 4;
    float sum = 0.f, mx = 0.f;
#pragma unroll
    for (int q = 0; q < 4; q++) {
        float4 h = hp[q]; float4 c = cp[q];
        h.x *= c.x; h.y *= c.y; h.z *= c.z; h.w *= c.w;
        hp[q] = h;
        sum += h.x + h.y + h.z + h.w;
        mx = fmaxf(mx, fmaxf(fmaxf(h.x, h.y), fmaxf(h.z, h.w)));
    }
    sum += __shfl_xor(sum, 1);
    mx = fmaxf(mx, __shfl_xor(mx, 1));
    if (hf == 0) {
        s2[v * 2 + 0] = sum * (1.0f / 32.0f);
        s2[v * 2 + 1] = mx;
    }
}

// ---- spatial attention: 2-ch sparse conv -> sigmoid; 4 thr/voxel ----
__global__ void k_saconv(const float* __restrict__ s2, const float* __restrict__ saW,
                         const int* __restrict__ nidx, const void* __restrict__ nmask,
                         const int* __restrict__ flag, float* __restrict__ sa) {
    __shared__ float w[KK * 2];
    if (threadIdx.x < KK * 2) w[threadIdx.x] = saW[threadIdx.x];
    __syncthreads();
    int t = blockIdx.x * 256 + threadIdx.x;
    int v = t >> 2, q = t & 3;
    if (v >= NVOX) return;
    int fl = *flag;
    float acc = 0.f;
#pragma unroll
    for (int j = 0; j < 7; j++) {
        int k = q + j * 4;
        if (k < KK) {
            int idx = nidx[k * NVOX + v];
            float m = get_mask(nmask, fl, (long)k * NVOX + v);
            float2 s = ((const float2*)s2)[idx];
            acc += m * (s.x * w[k * 2] + s.y * w[k * 2 + 1]);
        }
    }
    acc += __shfl_xor(acc, 1);
    acc += __shfl_xor(acc, 2);
    if (q == 0) sa[v] = 1.0f / (1.0f + expf(-acc));
}

// ---- gather to points, apply sa, classifier; 2 thr/point split over c ----
__global__ __launch_bounds__(256) void k_final(
        const float* __restrict__ h2, const float* __restrict__ sa,
        const int* __restrict__ p2v, const float* __restrict__ clsw,
        const float* __restrict__ clsb, float* __restrict__ out) {
    __shared__ float w[32 * 20];
    __shared__ float bb[20];
    for (int i = threadIdx.x; i < 640; i += 256) w[i] = clsw[i];
    if (threadIdx.x < 20) bb[threadIdx.x] = clsb[threadIdx.x];
    __syncthreads();
    int t = blockIdx.x * 256 + threadIdx.x;
    int p = t >> 1, ch = t & 1;
    if (p >= NPTS) return;
    int v = p2v[p];
    float s = sa[v];
    float acc[20];
#pragma unroll
    for (int j = 0; j < 20; j++) acc[j] = 0.f;
    const float4* hp = (const float4*)(h2 + (size_t)v * 32) + ch * 4;
#pragma unroll
    for (int q = 0; q < 4; q++) {
        float4 h = hp[q];
        int cb = (ch * 16 + q * 4) * 20;
        float z0 = h.x * s, z1 = h.y * s, z2 = h.z * s, z3 = h.w * s;
#pragma unroll
        for (int j = 0; j < 20; j++)
            acc[j] += z0 * w[cb + j] + z1 * w[cb + 20 + j]
                    + z2 * w[cb + 40 + j] + z3 * w[cb + 60 + j];
    }
#pragma unroll
    for (int j = 0; j < 20; j++) acc[j] += __shfl_xor(acc[j], 1);
    if (ch == 0) {
#pragma unroll
        for (int j = 0; j < 20; j++) out[(size_t)p * 20 + j] = acc[j] + bb[j];
    }
}

extern "C" void kernel_launch(void* const* d_in, const int* in_sizes, int n_in,
                              void* d_out, int out_size, void* d_ws, size_t ws_size,
                              hipStream_t stream) {
    const float* feat = (const float*)d_in[0];
    const float* W1   = (const float*)d_in[1];
    const float* g1   = (const float*)d_in[2];
    const float* b1   = (const float*)d_in[3];
    const float* W2   = (const float*)d_in[4];
    const float* g2   = (const float*)d_in[5];
    const float* b2   = (const float*)d_in[6];
    const float* caw1 = (const float*)d_in[7];
    const float* cab1 = (const float*)d_in[8];
    const float* caw2 = (const float*)d_in[9];
    const float* cab2 = (const float*)d_in[10];
    const float* saW  = (const float*)d_in[11];
    const float* clsw = (const float*)d_in[12];
    const float* clsb = (const float*)d_in[13];
    const int* p2v    = (const int*)d_in[14];
    const int* vb     = (const int*)d_in[15];
    const int* nidx   = (const int*)d_in[16];
    const void* nmask = d_in[17];
    float* out = (float*)d_out;

    int* flag   = (int*)d_ws;
    float* cnt  = (float*)d_ws + 64;              // 60000
    float* vox  = cnt + NVOX;                     // 240000 (sums -> averages in place)
    float* bsum = vox + (size_t)NVOX * 4;         // 128
    unsigned int* bmax = (unsigned int*)(bsum + NB * 32);  // 128
    float* bcnt = (float*)(bmax + NB * 32);       // 4
    float* ca   = bcnt + 64;                      // 128 (padded region)
    float* h1   = ca + 128;
    float* h2   = h1 + (size_t)NVOX * 32;
    float* s2   = h2 + (size_t)NVOX * 32;
    float* sa   = s2 + (size_t)NVOX * 2;

    int nzero = NVOX * 5 + NB * 32 * 2 + NB + 64;   // cnt..ca region
    k_init<<<512, 256, 0, stream>>>(cnt, nzero, (const unsigned int*)nmask, flag);
    k_scatter<<<(NPTS + 255) / 256, 256, 0, stream>>>((const float4*)feat, p2v, cnt, vox);
    k_voxdiv<<<(NVOX + 255) / 256, 256, 0, stream>>>(vox, cnt);
    k_conv1<<<(NVOX + 63) / 64, 256, 0, stream>>>(vox, W1, g1, b1, nidx, nmask, flag, h1);
    k_conv2<<<(NVOX + 127) / 128, 512, 0, stream>>>(h1, W2, g2, b2, nidx, nmask, flag, h2);
    k_pool<<<512, 256, 0, stream>>>(h2, vb, bsum, bmax, bcnt);
    k_ca<<<1, 64, 0, stream>>>(bsum, bmax, bcnt, caw1, cab1, caw2, cab2, ca);
    k_apply<<<(NVOX * 2 + 255) / 256, 256, 0, stream>>>(h2, ca, vb, s2);
    k_saconv<<<(NVOX * 4 + 255) / 256, 256, 0, stream>>>(s2, saW, nidx, nmask, flag, sa);
    k_final<<<(NPTS * 2 + 255) / 256, 256, 0, stream>>>(h2, sa, p2v, clsw, clsb, out);
}